// Round 1
// baseline (2456.677 us; speedup 1.0000x reference)
//
#include <hip/hip_runtime.h>
#include <math.h>

// Problem constants (from reference): N=2, C=256, H=W=48, HID=10, P=7
constexpr int NB_ = 2;
constexpr int C_  = 256;
constexpr int HW_ = 2304;   // 48*48

__device__ __forceinline__ float coordval(int c, int k) {
  int y = k / 48, x = k - y * 48;
  switch (c) {
    case 0: return x * (1.f/24.f) - 1.f;
    case 1: return y * (1.f/24.f) - 1.f;
    case 2: return (x + 1) * (1.f/24.f) - 1.f;
    case 3: return (y + 1) * (1.f/24.f) - 1.f;
    case 4: return (x + 0.5f) * (1.f/24.f) - 1.f;
    case 5: return (y + 0.5f) * (1.f/24.f) - 1.f;
    default: return 1.f/48.f;
  }
}

__device__ __forceinline__ float sigmoidf_(float x) { return 1.f / (1.f + expf(-x)); }

// ---------------------------------------------------------------------------
// K1: keydot[n*HW+k] = sum_d wk[d] * relu(sum_c dc_k_w[d,c]*cat[c] + b[d])
// block = 4 pixels x 64 d-lanes (one wave per pixel)
// ---------------------------------------------------------------------------
__global__ __launch_bounds__(256) void k_keydot(
    const float* __restrict__ xp, const float* __restrict__ dc_k_w,
    const float* __restrict__ dc_k_b, const float* __restrict__ dc_p_w,
    float* __restrict__ keydot)
{
  __shared__ float wl[64 * 265];
  __shared__ float xl[4][264];
  int t = threadIdx.x;
  for (int i = t; i < 64 * 264; i += 256) {
    int d = i / 264, c = i - d * 264;
    wl[d * 265 + c] = dc_k_w[i];
  }
  int p0 = blockIdx.x * 4;
  for (int i = t; i < 4 * 264; i += 256) {
    int pl = i & 3, c = i >> 2;
    int p = p0 + pl, n = p / HW_, k = p - n * HW_;
    xl[pl][c] = (c < 256) ? xp[(size_t)(n * C_ + c) * HW_ + k] : coordval(c - 256, k);
  }
  __syncthreads();
  int d = t & 63, pl = t >> 6;
  float acc = dc_k_b[d];
  const float* wr = &wl[d * 265];
  #pragma unroll 8
  for (int c = 0; c < 264; ++c) acc = fmaf(wr[c], xl[pl][c], acc);
  acc = fmaxf(acc, 0.f) * dc_p_w[64 + d];   // wk
  #pragma unroll
  for (int off = 32; off > 0; off >>= 1) acc += __shfl_down(acc, off, 64);
  if (d == 0) keydot[p0 + pl] = acc;
}

// ---------------------------------------------------------------------------
// K2: per (i in 0..5, n): softmax over HW of p_att[1+i], hu_c, co_c, q, qdot
// one block per (i,n); 12 blocks
// ---------------------------------------------------------------------------
__global__ __launch_bounds__(256) void k_ctxq(
    const float* __restrict__ xp, const float* __restrict__ p_att,
    const float* __restrict__ dc_q_w, const float* __restrict__ dc_q_b,
    const float* __restrict__ dc_p_w, float* __restrict__ qdot)
{
  __shared__ float na[HW_];
  __shared__ float red[16];
  __shared__ float hu[256];
  __shared__ float co[8];
  __shared__ float ql[64];
  int t = threadIdx.x;
  int i = blockIdx.x / NB_, n = blockIdx.x % NB_;
  const float* att = p_att + (size_t)((1 + i) * NB_ + n) * HW_;

  float m = -1e30f;
  for (int k = t; k < HW_; k += 256) m = fmaxf(m, att[k]);
  #pragma unroll
  for (int off = 32; off > 0; off >>= 1) m = fmaxf(m, __shfl_down(m, off, 64));
  if ((t & 63) == 0) red[t >> 6] = m;
  __syncthreads();
  if (t == 0) { float mm = red[0]; for (int w = 1; w < 4; ++w) mm = fmaxf(mm, red[w]); red[0] = mm; }
  __syncthreads();
  m = red[0];
  float s = 0.f;
  for (int k = t; k < HW_; k += 256) { float e = expf(att[k] - m); na[k] = e; s += e; }
  #pragma unroll
  for (int off = 32; off > 0; off >>= 1) s += __shfl_down(s, off, 64);
  if ((t & 63) == 0) red[8 + (t >> 6)] = s;
  __syncthreads();
  if (t == 0) { float ss = 0; for (int w = 0; w < 4; ++w) ss += red[8 + w]; red[8] = ss; }
  __syncthreads();
  float inv = 1.f / red[8];
  for (int k = t; k < HW_; k += 256) na[k] *= inv;
  __syncthreads();

  { // hu_c[c], thread t = channel c
    const float4* xr = (const float4*)(xp + (size_t)(n * C_ + t) * HW_);
    float a = 0.f;
    for (int k = 0; k < HW_ / 4; ++k) {
      float4 v = xr[k];
      a += v.x * na[4*k] + v.y * na[4*k+1] + v.z * na[4*k+2] + v.w * na[4*k+3];
    }
    hu[t] = a;
  }
  if (t < 8) { float a = 0.f; for (int k = 0; k < HW_; ++k) a += coordval(t, k) * na[k]; co[t] = a; }
  __syncthreads();

  if (t < 64) {
    float a = dc_q_b[t];
    const float* wr = dc_q_w + (size_t)t * 264;
    for (int c = 0; c < 256; ++c) a = fmaf(wr[c], hu[c], a);
    #pragma unroll
    for (int c = 0; c < 8; ++c) a = fmaf(wr[256 + c], co[c], a);
    ql[t] = fmaxf(a, 0.f) * dc_p_w[t];   // wq
  }
  __syncthreads();
  if (t == 0) {
    float a = 0.f;
    for (int d = 0; d < 64; ++d) a += ql[d];
    qdot[blockIdx.x] = a;   // [i*NB + n]
  }
}

// ---------------------------------------------------------------------------
// K3: dep_att[e][n][k] = sigmoid(qdot + keydot + b) * (1 - p_att[1+e])
// ---------------------------------------------------------------------------
__global__ __launch_bounds__(256) void k_depatt(
    const float* __restrict__ p_att, const float* __restrict__ keydot,
    const float* __restrict__ qdot, const float* __restrict__ dc_p_b,
    float* __restrict__ dep_att)
{
  int idx = blockIdx.x * 256 + threadIdx.x;
  if (idx >= 6 * NB_ * HW_) return;
  int e = idx / (NB_ * HW_); int r = idx - e * NB_ * HW_;
  int n = r / HW_, k = r - n * HW_;
  float energy = qdot[e * NB_ + n] + keydot[n * HW_ + k] + dc_p_b[0];
  float a = sigmoidf_(energy);
  float hu = p_att[(size_t)((1 + e) * NB_ + n) * HW_ + k];
  dep_att[idx] = a * (1.f - hu);
}

// ---------------------------------------------------------------------------
// K4: rpx[n][d][k] = relu(sum_c dp_proj[d,c]*xp[n,c,k])
// ---------------------------------------------------------------------------
__global__ __launch_bounds__(256) void k_rpx(
    const float* __restrict__ xp, const float* __restrict__ dp_proj,
    float* __restrict__ rpx)
{
  __shared__ float pj[10 * 256];
  int t = threadIdx.x;
  for (int i = t; i < 2560; i += 256) pj[i] = dp_proj[i];
  __syncthreads();
  int p = blockIdx.x * 256 + t;
  if (p >= NB_ * HW_) return;
  int n = p / HW_, k = p - n * HW_;
  float acc[10];
  #pragma unroll
  for (int d = 0; d < 10; ++d) acc[d] = 0.f;
  const float* x = xp + (size_t)n * C_ * HW_ + k;
  for (int c = 0; c < 256; ++c) {
    float v = x[(size_t)c * HW_];
    #pragma unroll
    for (int d = 0; d < 10; ++d) acc[d] = fmaf(pj[d * 256 + c], v, acc[d]);
  }
  #pragma unroll
  for (int d = 0; d < 10; ++d) rpx[(size_t)(n * 10 + d) * HW_ + k] = fmaxf(acc[d], 0.f);
}

// ---------------------------------------------------------------------------
// K5: the 8 big 257->256 3x3 convs, relu, fused partial 1x1 head per ocb.
// grid = inst(8) x n(2) x ocb(4) x tile(36 of 8x8). block=256.
// thread: 2 oc x 8 px accumulators.
// parc[(((inst*NB+n)*4+ocb)*5+d)*HW + k] = partial head sums (deterministic)
// ---------------------------------------------------------------------------
__global__ __launch_bounds__(256) void k_bigconv(
    const float* __restrict__ xp, const float* __restrict__ dep_att,
    const float* __restrict__ h_att,
    const float* __restrict__ ctx_w1, const float* __restrict__ du_a1,
    const float* __restrict__ dl_a1,
    const float* __restrict__ ctx_w2, const float* __restrict__ du_a2,
    const float* __restrict__ dl_a2,
    float* __restrict__ parc)
{
  int b = blockIdx.x;
  int tile = b % 36; b /= 36;
  int ocb = b % 4;   b /= 4;
  int n = b % NB_;   b /= NB_;
  int inst = b;                       // 0..7
  int ty0 = (tile / 6) * 8, tx0 = (tile % 6) * 8;

  __shared__ float xs[8 * 10 * 20];       // [ic][ry][rx pad 20] (bank-safe, 16B-aligned rows)
  __shared__ float wl[8 * 3 * 32 * 6];    // [ic][kh][ocp][o2*3+kw]
  __shared__ float hbuf[64][65];          // relu(h1) for head reduction

  const float* wsrc; const float* asrc;
  if (inst < 6)      { wsrc = ctx_w1 + (size_t)inst * 256 * 257 * 9; asrc = dep_att + (size_t)(inst * NB_ + n) * HW_; }
  else if (inst == 6){ wsrc = du_a1;  asrc = h_att + (size_t)(1 * NB_ + n) * HW_; }
  else               { wsrc = dl_a1;  asrc = h_att + (size_t)(2 * NB_ + n) * HW_; }

  int t = threadIdx.x;
  int rowi = t & 7, ocp = t >> 3;     // ocp 0..31
  float acc[2][8];
  #pragma unroll
  for (int a = 0; a < 2; ++a)
    #pragma unroll
    for (int p = 0; p < 8; ++p) acc[a][p] = 0.f;

  const float* xpn = xp + (size_t)n * C_ * HW_;

  for (int chunk = 0; chunk < 33; ++chunk) {
    // stage input 8ch x 10x10 halo
    for (int i = t; i < 800; i += 256) {
      int ic = i / 100; int rr = (i - ic * 100) / 10; int xx = i % 10;
      int c = chunk * 8 + ic;
      int gy = ty0 + rr - 1, gx = tx0 + xx - 1;
      float v = 0.f;
      if (c < 257 && gy >= 0 && gy < 48 && gx >= 0 && gx < 48) {
        int kk = gy * 48 + gx;
        v = (c == 0) ? asrc[kk] : xpn[(size_t)(c - 1) * HW_ + kk];
      }
      xs[(ic * 10 + rr) * 20 + xx] = v;
    }
    // stage weights (coalesced read: 72 contiguous floats per oc)
    for (int i = t; i < 4608; i += 256) {
      int ocl = i / 72; int q = i - ocl * 72;
      int cl = q / 9;   int kk = q - cl * 9;
      int kh = kk / 3,  kw = kk - kh * 3;
      int c = chunk * 8 + cl;
      float v = 0.f;
      if (c < 257) v = wsrc[((size_t)(ocb * 64 + ocl) * 257 + c) * 9 + kk];
      wl[((cl * 3 + kh) * 32 + (ocl >> 1)) * 6 + (ocl & 1) * 3 + kw] = v;
    }
    __syncthreads();

    #pragma unroll 2
    for (int ic = 0; ic < 8; ++ic) {
      #pragma unroll
      for (int kh = 0; kh < 3; ++kh) {
        float xr[10];
        const float* xrow = &xs[(ic * 10 + rowi + kh) * 20];
        #pragma unroll
        for (int q = 0; q < 10; ++q) xr[q] = xrow[q];
        float wv[6];
        const float* wrow = &wl[((ic * 3 + kh) * 32 + ocp) * 6];
        #pragma unroll
        for (int q = 0; q < 6; ++q) wv[q] = wrow[q];
        #pragma unroll
        for (int kw = 0; kw < 3; ++kw) {
          #pragma unroll
          for (int p = 0; p < 8; ++p) {
            float xv = xr[p + kw];
            acc[0][p] = fmaf(wv[kw],     xv, acc[0][p]);
            acc[1][p] = fmaf(wv[3 + kw], xv, acc[1][p]);
          }
        }
      }
    }
    __syncthreads();
  }

  // relu -> hbuf
  int oc0 = ocp * 2;
  #pragma unroll
  for (int p = 0; p < 8; ++p) {
    hbuf[oc0][rowi * 8 + p]     = fmaxf(acc[0][p], 0.f);
    hbuf[oc0 + 1][rowi * 8 + p] = fmaxf(acc[1][p], 0.f);
  }
  __syncthreads();

  // fused 1x1 head partial over this block's 64 oc
  int nd = (inst < 6) ? 5 : (inst == 6 ? 4 : 2);
  const float* w2 = (inst < 6) ? (ctx_w2 + (size_t)inst * 5 * 256)
                               : (inst == 6 ? du_a2 : dl_a2);
  float* parcp = parc + (((size_t)(inst * NB_ + n) * 4 + ocb) * 5) * HW_;
  if (t < 64) {
    int py = t >> 3, px = t & 7;
    int k = (ty0 + py) * 48 + tx0 + px;
    for (int d = 0; d < nd; ++d) {
      const float* wrow = w2 + (size_t)d * 256 + ocb * 64;
      float s = 0.f;
      #pragma unroll 8
      for (int oc = 0; oc < 64; ++oc) s = fmaf(wrow[oc], hbuf[oc][t], s);
      parcp[(size_t)d * HW_ + k] = s;
    }
  }
}

// ---------------------------------------------------------------------------
// K6: finalize heads (sum 4 ocb partials + bias), write raw outputs, softmax
// ---------------------------------------------------------------------------
__global__ __launch_bounds__(256) void k_heads(
    const float* __restrict__ parc,
    const float* __restrict__ ctx_b2, const float* __restrict__ du_a2b,
    const float* __restrict__ dl_a2b,
    float* __restrict__ out_fdep, float* __restrict__ out_du, float* __restrict__ out_dl,
    float* __restrict__ att_sm, float* __restrict__ da_u, float* __restrict__ da_l)
{
  int idx = blockIdx.x * 256 + threadIdx.x;
  if (idx >= 8 * NB_ * HW_) return;
  int inst = idx / (NB_ * HW_); int r = idx - inst * (NB_ * HW_);
  int n = r / HW_, k = r - n * HW_;
  const float* base = parc + (((size_t)(inst * NB_ + n) * 4) * 5) * HW_ + k;
  int nd = (inst < 6) ? 5 : (inst == 6 ? 4 : 2);
  float v[5];
  float mx = -1e30f;
  for (int d = 0; d < nd; ++d) {
    float s = 0.f;
    for (int o = 0; o < 4; ++o) s += base[((size_t)o * 5 + d) * HW_];
    if (inst < 6) s += ctx_b2[inst * 5 + d];
    else if (inst == 6) s += du_a2b[d];
    else s += dl_a2b[d];
    v[d] = s;
    mx = fmaxf(mx, s);
    if (inst < 6)      out_fdep[((size_t)(inst * NB_ + n) * 5 + d) * HW_ + k] = s;
    else if (inst == 6) out_du[((size_t)n * 4 + d) * HW_ + k] = s;
    else                out_dl[((size_t)n * 2 + d) * HW_ + k] = s;
  }
  float ssum = 0.f;
  for (int d = 0; d < nd; ++d) { v[d] = expf(v[d] - mx); ssum += v[d]; }
  float is = 1.f / ssum;
  for (int d = 0; d < nd; ++d) {
    float sm = v[d] * is;
    if (inst < 6)      att_sm[((size_t)(inst * NB_ + n) * 5 + d) * HW_ + k] = sm;
    else if (inst == 6) da_u[((size_t)n * 4 + d) * HW_ + k] = sm;
    else                da_l[((size_t)n * 2 + d) * HW_ + k] = sm;
  }
}

// ---------------------------------------------------------------------------
// K7: dep messages + segment_sum -> xpp[v][n][10][HW]
// grid = v(6) x n(2) x tile(9 of 16x16); loops 5 incoming edges in-register
// ---------------------------------------------------------------------------
__global__ __launch_bounds__(256) void k_msgs(
    const float* __restrict__ p_nodes, const float* __restrict__ att_sm,
    const float* __restrict__ dep_att, const float* __restrict__ rpx,
    const float* __restrict__ dp_r1, const float* __restrict__ dp_r2,
    const float* __restrict__ dp_r2b, float* __restrict__ xpp)
{
  int b = blockIdx.x;
  int tile = b % 9; b /= 9;
  int n = b % NB_;  int v = b / NB_;   // v 0..5
  int ty0 = (tile / 3) * 16, tx0 = (tile % 3) * 16;
  __shared__ float xt[20][18][20];
  __shared__ float wl[1800];
  __shared__ float w2l[100];
  __shared__ float b2l[10];
  int t = threadIdx.x;
  for (int i = t; i < 1800; i += 256) wl[i] = dp_r1[i];
  for (int i = t; i < 100; i += 256) w2l[i] = dp_r2[i];
  if (t < 10) b2l[t] = dp_r2b[t];
  // stage hv = p_nodes[v] (channels 10..19), once
  for (int i = t; i < 10 * 324; i += 256) {
    int d = i / 324; int rr = (i % 324) / 18; int cc = i % 18;
    int gy = ty0 + rr - 1, gx = tx0 + cc - 1;
    float val = 0.f;
    if (gy >= 0 && gy < 48 && gx >= 0 && gx < 48)
      val = p_nodes[((size_t)(v * NB_ + n) * 10 + d) * HW_ + gy * 48 + gx];
    xt[10 + d][rr][cc] = val;
  }
  int rr = t >> 4, cc = t & 15;
  int k = (ty0 + rr) * 48 + tx0 + cc;
  float msum[10];
  #pragma unroll
  for (int d = 0; d < 10; ++d) msum[d] = 0.f;

  for (int u = 0; u < 6; ++u) {
    if (u == v) continue;
    int ce = (v < u) ? v : v - 1;
    __syncthreads();  // previous compute done before overwriting m channels
    const float* asrc = att_sm + ((size_t)(u * NB_ + n) * 5 + ce) * HW_;
    const float* dsrc = dep_att + (size_t)(u * NB_ + n) * HW_;
    for (int i = t; i < 10 * 324; i += 256) {
      int d = i / 324; int r2 = (i % 324) / 18; int c2 = i % 18;
      int gy = ty0 + r2 - 1, gx = tx0 + c2 - 1;
      float val = 0.f;
      if (gy >= 0 && gy < 48 && gx >= 0 && gx < 48) {
        int kk = gy * 48 + gx;
        val = asrc[kk] * dsrc[kk] * rpx[((size_t)n * 10 + d) * HW_ + kk];
      }
      xt[d][r2][c2] = val;
    }
    __syncthreads();
    float y[10];
    #pragma unroll
    for (int d = 0; d < 10; ++d) y[d] = 0.f;
    for (int ic = 0; ic < 20; ++ic)
      #pragma unroll
      for (int kh = 0; kh < 3; ++kh)
        #pragma unroll
        for (int kw = 0; kw < 3; ++kw) {
          float xv = xt[ic][rr + kh][cc + kw];
          #pragma unroll
          for (int d = 0; d < 10; ++d)
            y[d] = fmaf(wl[(d * 20 + ic) * 9 + kh * 3 + kw], xv, y[d]);
        }
    #pragma unroll
    for (int d = 0; d < 10; ++d) y[d] = fmaxf(y[d], 0.f);
    #pragma unroll
    for (int d = 0; d < 10; ++d) {
      float s = b2l[d];
      #pragma unroll
      for (int j = 0; j < 10; ++j) s = fmaf(w2l[d * 10 + j], y[j], s);
      msum[d] += sigmoidf_(s);
    }
  }
  #pragma unroll
  for (int d = 0; d < 10; ++d)
    xpp[((size_t)(v * NB_ + n) * 10 + d) * HW_ + k] = msum[d];
}

// ---------------------------------------------------------------------------
// K8: du/dl parts conv + combine with alpha*xpp + GRU  (nodes 1..6)
// ---------------------------------------------------------------------------
__global__ __launch_bounds__(256) void k_parts_gru(
    const float* __restrict__ h_nodes, const float* __restrict__ p_nodes,
    const float* __restrict__ h_att,
    const float* __restrict__ da_u, const float* __restrict__ da_l,
    const float* __restrict__ du_r1, const float* __restrict__ du_r2,
    const float* __restrict__ dl_r1, const float* __restrict__ dl_r2,
    const float* __restrict__ xpp, const float* __restrict__ alpha,
    const float* __restrict__ gru_gw, const float* __restrict__ gru_gb,
    const float* __restrict__ gru_cw, float* __restrict__ p_new)
{
  int b = blockIdx.x;
  int tile = b % 9; b /= 9;
  int n = b % NB_;  int vp = b / NB_ + 1;   // node 1..6
  int ty0 = (tile / 3) * 16, tx0 = (tile % 3) * 16;
  bool isU = (vp <= 4);
  int j = isU ? vp - 1 : vp - 5;
  const float* parent = h_nodes + ((size_t)((isU ? 1 : 2) * NB_ + n) * 10) * HW_;
  const float* patt   = h_att + (size_t)((isU ? 1 : 2) * NB_ + n) * HW_;
  const float* da     = isU ? (da_u + ((size_t)n * 4 + j) * HW_) : (da_l + ((size_t)n * 2 + j) * HW_);
  const float* child  = p_nodes + (size_t)(vp * NB_ + n) * 10 * HW_;
  const float* r1 = isU ? du_r1 : dl_r1;
  const float* r2 = isU ? du_r2 : dl_r2;

  __shared__ float xt[20][18][20];
  __shared__ float wl[1800];
  __shared__ float w2l[100];
  int t = threadIdx.x;
  for (int i = t; i < 1800; i += 256) wl[i] = r1[i];
  for (int i = t; i < 100; i += 256) w2l[i] = r2[i];
  for (int i = t; i < 20 * 324; i += 256) {
    int d = i / 324; int rr = (i % 324) / 18; int cc = i % 18;
    int gy = ty0 + rr - 1, gx = tx0 + cc - 1;
    float val = 0.f;
    if (gy >= 0 && gy < 48 && gx >= 0 && gx < 48) {
      int kk = gy * 48 + gx;
      val = (d < 10) ? parent[(size_t)d * HW_ + kk] * da[kk] * patt[kk]
                     : child[(size_t)(d - 10) * HW_ + kk];
    }
    xt[d][rr][cc] = val;
  }
  __syncthreads();
  int rr = t >> 4, cc = t & 15;
  int k = (ty0 + rr) * 48 + tx0 + cc;
  float y[10];
  #pragma unroll
  for (int d = 0; d < 10; ++d) y[d] = 0.f;
  for (int ic = 0; ic < 20; ++ic)
    #pragma unroll
    for (int kh = 0; kh < 3; ++kh)
      #pragma unroll
      for (int kw = 0; kw < 3; ++kw) {
        float xv = xt[ic][rr + kh][cc + kw];
        #pragma unroll
        for (int d = 0; d < 10; ++d)
          y[d] = fmaf(wl[(d * 20 + ic) * 9 + kh * 3 + kw], xv, y[d]);
      }
  float yr[10];
  #pragma unroll
  for (int d = 0; d < 10; ++d) yr[d] = fmaxf(y[d], 0.f);

  float al = alpha[0];
  float x[10], h[10];
  #pragma unroll
  for (int d = 0; d < 10; ++d) {
    float s = 0.f;
    #pragma unroll
    for (int jj = 0; jj < 10; ++jj) s = fmaf(w2l[d * 10 + jj], yr[jj], s);
    float parts = fmaxf(s, 0.f);
    x[d] = parts + al * xpp[((size_t)((vp - 1) * NB_ + n) * 10 + d) * HW_ + k];
    h[d] = p_nodes[((size_t)(vp * NB_ + n) * 10 + d) * HW_ + k];
  }
  const float* gw = gru_gw + (size_t)vp * 40;
  const float* gb = gru_gb + (size_t)vp * 2;
  const float* cw = gru_cw + (size_t)vp * 200;
  float g0 = gb[0], g1 = gb[1];
  #pragma unroll
  for (int d = 0; d < 10; ++d) {
    g0 = fmaf(gw[d], x[d], fmaf(gw[10 + d], h[d], g0));
    g1 = fmaf(gw[20 + d], x[d], fmaf(gw[30 + d], h[d], g1));
  }
  float rg = sigmoidf_(g0);
  float ug = sigmoidf_(g1);
  #pragma unroll
  for (int d = 0; d < 10; ++d) {
    float s = 0.f;
    const float* cr = cw + d * 20;
    #pragma unroll
    for (int jj = 0; jj < 10; ++jj)
      s = fmaf(cr[jj], x[jj], fmaf(cr[10 + jj], rg * h[jj], s));
    float cn = fmaxf(s, 0.f);
    p_new[((size_t)(vp * NB_ + n) * 10 + d) * HW_ + k] = (1.f - ug) * h[d] + ug * cn;
  }
}

// ---------------------------------------------------------------------------
// K9: GRU for node 0 (x = h_nodes[0])
// ---------------------------------------------------------------------------
__global__ __launch_bounds__(256) void k_gru0(
    const float* __restrict__ h_nodes, const float* __restrict__ p_nodes,
    const float* __restrict__ gru_gw, const float* __restrict__ gru_gb,
    const float* __restrict__ gru_cw, float* __restrict__ p_new)
{
  int idx = blockIdx.x * 256 + threadIdx.x;
  if (idx >= NB_ * HW_) return;
  int n = idx / HW_, k = idx - n * HW_;
  float x[10], h[10];
  #pragma unroll
  for (int d = 0; d < 10; ++d) {
    x[d] = h_nodes[((size_t)(0 * NB_ + n) * 10 + d) * HW_ + k];
    h[d] = p_nodes[((size_t)(0 * NB_ + n) * 10 + d) * HW_ + k];
  }
  const float* gw = gru_gw;
  const float* gb = gru_gb;
  const float* cw = gru_cw;
  float g0 = gb[0], g1 = gb[1];
  #pragma unroll
  for (int d = 0; d < 10; ++d) {
    g0 = fmaf(gw[d], x[d], fmaf(gw[10 + d], h[d], g0));
    g1 = fmaf(gw[20 + d], x[d], fmaf(gw[30 + d], h[d], g1));
  }
  float rg = sigmoidf_(g0);
  float ug = sigmoidf_(g1);
  #pragma unroll
  for (int d = 0; d < 10; ++d) {
    float s = 0.f;
    const float* cr = cw + d * 20;
    #pragma unroll
    for (int jj = 0; jj < 10; ++jj)
      s = fmaf(cr[jj], x[jj], fmaf(cr[10 + jj], rg * h[jj], s));
    float cn = fmaxf(s, 0.f);
    p_new[((size_t)(0 * NB_ + n) * 10 + d) * HW_ + k] = (1.f - ug) * h[d] + ug * cn;
  }
}

// ---------------------------------------------------------------------------
extern "C" void kernel_launch(void* const* d_in, const int* in_sizes, int n_in,
                              void* d_out, int out_size, void* d_ws, size_t ws_size,
                              hipStream_t stream) {
  (void)in_sizes; (void)n_in; (void)out_size; (void)ws_size;
  const float* h_nodes = (const float*)d_in[1];
  const float* p_nodes = (const float*)d_in[2];
  const float* xp      = (const float*)d_in[3];
  const float* h_att   = (const float*)d_in[4];
  const float* p_att   = (const float*)d_in[5];
  const float* dc_q_w  = (const float*)d_in[6];
  const float* dc_q_b  = (const float*)d_in[7];
  const float* dc_k_w  = (const float*)d_in[8];
  const float* dc_k_b  = (const float*)d_in[9];
  const float* dc_p_w  = (const float*)d_in[10];
  const float* dc_p_b  = (const float*)d_in[11];
  const float* ctx_w1  = (const float*)d_in[12];
  const float* ctx_w2  = (const float*)d_in[13];
  const float* ctx_b2  = (const float*)d_in[14];
  const float* du_a1   = (const float*)d_in[15];
  const float* du_a2   = (const float*)d_in[16];
  const float* du_a2b  = (const float*)d_in[17];
  const float* du_r1   = (const float*)d_in[18];
  const float* du_r2   = (const float*)d_in[19];
  const float* dl_a1   = (const float*)d_in[20];
  const float* dl_a2   = (const float*)d_in[21];
  const float* dl_a2b  = (const float*)d_in[22];
  const float* dl_r1   = (const float*)d_in[23];
  const float* dl_r2   = (const float*)d_in[24];
  const float* dp_proj = (const float*)d_in[25];
  const float* dp_r1   = (const float*)d_in[26];
  const float* dp_r2   = (const float*)d_in[27];
  const float* dp_r2b  = (const float*)d_in[28];
  const float* gru_gw  = (const float*)d_in[29];
  const float* gru_gb  = (const float*)d_in[30];
  const float* gru_cw  = (const float*)d_in[31];
  const float* alpha   = (const float*)d_in[32];

  float* ws = (float*)d_ws;
  float* keydot  = ws;                 // 4608
  float* qdot    = ws + 4608;          // 12
  float* dep_att = ws + 4620;          // 27648
  float* rpx     = ws + 32268;         // 46080
  float* parc    = ws + 78348;         // 737280 (8*2*4*5*2304)
  float* att_sm  = ws + 815628;        // 138240
  float* da_u    = ws + 953868;        // 18432
  float* da_l    = ws + 972300;        // 9216
  float* xpp     = ws + 981516;        // 276480  -> total 1257996 floats (~5 MB)

  float* out      = (float*)d_out;
  float* out_pnew = out;               // 322560
  float* out_du   = out + 322560;      // 18432
  float* out_dl   = out + 340992;      // 9216
  float* out_fdep = out + 350208;      // 138240

  k_keydot<<<1152, 256, 0, stream>>>(xp, dc_k_w, dc_k_b, dc_p_w, keydot);
  k_ctxq<<<12, 256, 0, stream>>>(xp, p_att, dc_q_w, dc_q_b, dc_p_w, qdot);
  k_depatt<<<108, 256, 0, stream>>>(p_att, keydot, qdot, dc_p_b, dep_att);
  k_rpx<<<18, 256, 0, stream>>>(xp, dp_proj, rpx);
  k_bigconv<<<2304, 256, 0, stream>>>(xp, dep_att, h_att, ctx_w1, du_a1, dl_a1,
                                      ctx_w2, du_a2, dl_a2, parc);
  k_heads<<<144, 256, 0, stream>>>(parc, ctx_b2, du_a2b, dl_a2b,
                                   out_fdep, out_du, out_dl, att_sm, da_u, da_l);
  k_msgs<<<108, 256, 0, stream>>>(p_nodes, att_sm, dep_att, rpx,
                                  dp_r1, dp_r2, dp_r2b, xpp);
  k_parts_gru<<<108, 256, 0, stream>>>(h_nodes, p_nodes, h_att, da_u, da_l,
                                       du_r1, du_r2, dl_r1, dl_r2, xpp, alpha,
                                       gru_gw, gru_gb, gru_cw, out_pnew);
  k_gru0<<<18, 256, 0, stream>>>(h_nodes, p_nodes, gru_gw, gru_gb, gru_cw, out_pnew);
}

// Round 2
// 954.503 us; speedup vs baseline: 2.5738x; 2.5738x over previous
//
#include <hip/hip_runtime.h>
#include <math.h>

// Problem constants: N=2, C=256, H=W=48, HID=10, P=7
constexpr int NB_ = 2;
constexpr int C_  = 256;
constexpr int HW_ = 2304;   // 48*48

typedef float f32x4 __attribute__((ext_vector_type(4)));
typedef short short8 __attribute__((ext_vector_type(8)));

__device__ __forceinline__ float coordval(int c, int k) {
  int y = k / 48, x = k - y * 48;
  switch (c) {
    case 0: return x * (1.f/24.f) - 1.f;
    case 1: return y * (1.f/24.f) - 1.f;
    case 2: return (x + 1) * (1.f/24.f) - 1.f;
    case 3: return (y + 1) * (1.f/24.f) - 1.f;
    case 4: return (x + 0.5f) * (1.f/24.f) - 1.f;
    case 5: return (y + 0.5f) * (1.f/24.f) - 1.f;
    default: return 1.f/48.f;
  }
}

__device__ __forceinline__ float sigmoidf_(float x) { return 1.f / (1.f + expf(-x)); }
__device__ __forceinline__ unsigned short f2bf(float f) {
  unsigned int u = __float_as_uint(f);
  unsigned int r = (u + 0x7FFFu + ((u >> 16) & 1u)) >> 16;
  return (unsigned short)r;
}
__device__ __forceinline__ float bf2f(unsigned short h) {
  return __uint_as_float(((unsigned int)h) << 16);
}

// ---------------------------------------------------------------------------
// P1: xbf[n][y][x][c] = bf16(xp[n][c][y*48+x])   (NHWC bf16)
// ---------------------------------------------------------------------------
__global__ __launch_bounds__(256) void k_xbf(
    const float* __restrict__ xp, unsigned short* __restrict__ xbf)
{
  __shared__ float xt[64][65];
  int t = threadIdx.x;
  int px0 = blockIdx.x * 64;
  int n = px0 / HW_, k0 = px0 - n * HW_;
  for (int cb = 0; cb < 4; ++cb) {
    __syncthreads();
    for (int i = t; i < 4096; i += 256) {
      int cl = i >> 6, pxl = i & 63;
      xt[cl][pxl] = xp[((size_t)(n * C_ + cb * 64 + cl)) * HW_ + k0 + pxl];
    }
    __syncthreads();
    for (int i = t; i < 4096; i += 256) {
      int pxl = i >> 6, cl = i & 63;
      xbf[((size_t)(n * HW_ + k0 + pxl)) * 256 + cb * 64 + cl] = f2bf(xt[cl][pxl]);
    }
  }
}

// ---------------------------------------------------------------------------
// P2: weight transform.
// wt[((inst*9+pos)*256+oc)*256 + c] = bf16(w1[oc][c+1][pos])  (c = xp channel)
// w0[(inst*256+oc)*9+pos] = w1[oc][0][pos]                    (att channel)
// ---------------------------------------------------------------------------
__global__ __launch_bounds__(256) void k_wbf(
    const float* __restrict__ ctx_w1, const float* __restrict__ du_a1,
    const float* __restrict__ dl_a1,
    unsigned short* __restrict__ wt, float* __restrict__ w0)
{
  int inst = blockIdx.x >> 8, oc = blockIdx.x & 255;
  const float* src = (inst < 6) ? (ctx_w1 + (size_t)inst * 256 * 2313)
                   : (inst == 6 ? du_a1 : dl_a1);
  src += (size_t)oc * 2313;
  int t = threadIdx.x;
  for (int i = t; i < 2304; i += 256) {
    int pos = i >> 8, c = i & 255;
    float v = src[(size_t)(c + 1) * 9 + pos];
    wt[((size_t)(inst * 9 + pos) * 256 + oc) * 256 + c] = f2bf(v);
  }
  if (t < 9) w0[((size_t)inst * 256 + oc) * 9 + t] = src[t];
}

// ---------------------------------------------------------------------------
// K1: keydot[p] = sum_d wk[d] * relu(sum_c dc_k_w[d,c]*cat[c] + b[d])
// 288 blocks x 16 px. lane = d (64), wave-group strip of 4 px.
// ---------------------------------------------------------------------------
__global__ __launch_bounds__(256) void k_keydot(
    const unsigned short* __restrict__ xbf, const float* __restrict__ dc_k_w,
    const float* __restrict__ dc_k_b, const float* __restrict__ dc_p_w,
    float* __restrict__ keydot)
{
  __shared__ unsigned short wl[264 * 64];   // [c][d] bf16
  __shared__ float xl[16][265];
  __shared__ float wkl[64], bl[64];
  int t = threadIdx.x;
  for (int i = t; i < 64 * 264; i += 256) {
    int d = i / 264, c = i - d * 264;
    wl[c * 64 + d] = f2bf(dc_k_w[i]);
  }
  if (t < 64) { wkl[t] = dc_p_w[64 + t]; bl[t] = dc_k_b[t]; }
  int p0 = blockIdx.x * 16;
  for (int i = t; i < 16 * 264; i += 256) {
    int pl = i / 264, c = i - pl * 264;
    int p = p0 + pl, n = p / HW_, k = p - n * HW_;
    xl[pl][c] = (c < 256) ? bf2f(xbf[((size_t)(n * HW_ + k)) * 256 + c])
                          : coordval(c - 256, k);
  }
  __syncthreads();
  int d = t & 63, wg = t >> 6;
  for (int q = 0; q < 4; ++q) {
    int pl = wg * 4 + q;
    float a = bl[d];
    for (int c = 0; c < 264; ++c) a = fmaf(bf2f(wl[c * 64 + d]), xl[pl][c], a);
    a = fmaxf(a, 0.f) * wkl[d];
    #pragma unroll
    for (int off = 32; off > 0; off >>= 1) a += __shfl_down(a, off, 64);
    if (d == 0) keydot[p0 + pl] = a;
  }
}

// ---------------------------------------------------------------------------
// K2: per (i in 0..5, n): softmax over HW, hu_c, co_c, q, qdot   (12 blocks)
// ---------------------------------------------------------------------------
__global__ __launch_bounds__(256) void k_ctxq(
    const float* __restrict__ xp, const float* __restrict__ p_att,
    const float* __restrict__ dc_q_w, const float* __restrict__ dc_q_b,
    const float* __restrict__ dc_p_w, float* __restrict__ qdot)
{
  __shared__ float na[HW_];
  __shared__ float red[16];
  __shared__ float hu[256];
  __shared__ float co[8];
  __shared__ float ql[64];
  int t = threadIdx.x;
  int i = blockIdx.x / NB_, n = blockIdx.x % NB_;
  const float* att = p_att + (size_t)((1 + i) * NB_ + n) * HW_;

  float m = -1e30f;
  for (int k = t; k < HW_; k += 256) m = fmaxf(m, att[k]);
  #pragma unroll
  for (int off = 32; off > 0; off >>= 1) m = fmaxf(m, __shfl_down(m, off, 64));
  if ((t & 63) == 0) red[t >> 6] = m;
  __syncthreads();
  if (t == 0) { float mm = red[0]; for (int w = 1; w < 4; ++w) mm = fmaxf(mm, red[w]); red[0] = mm; }
  __syncthreads();
  m = red[0];
  float s = 0.f;
  for (int k = t; k < HW_; k += 256) { float e = expf(att[k] - m); na[k] = e; s += e; }
  #pragma unroll
  for (int off = 32; off > 0; off >>= 1) s += __shfl_down(s, off, 64);
  if ((t & 63) == 0) red[8 + (t >> 6)] = s;
  __syncthreads();
  if (t == 0) { float ss = 0; for (int w = 0; w < 4; ++w) ss += red[8 + w]; red[8] = ss; }
  __syncthreads();
  float inv = 1.f / red[8];
  for (int k = t; k < HW_; k += 256) na[k] *= inv;
  __syncthreads();

  {
    const float4* xr = (const float4*)(xp + (size_t)(n * C_ + t) * HW_);
    float a = 0.f;
    for (int k = 0; k < HW_ / 4; ++k) {
      float4 v = xr[k];
      a += v.x * na[4*k] + v.y * na[4*k+1] + v.z * na[4*k+2] + v.w * na[4*k+3];
    }
    hu[t] = a;
  }
  if (t < 8) { float a = 0.f; for (int k = 0; k < HW_; ++k) a += coordval(t, k) * na[k]; co[t] = a; }
  __syncthreads();

  if (t < 64) {
    float a = dc_q_b[t];
    const float* wr = dc_q_w + (size_t)t * 264;
    for (int c = 0; c < 256; ++c) a = fmaf(wr[c], hu[c], a);
    #pragma unroll
    for (int c = 0; c < 8; ++c) a = fmaf(wr[256 + c], co[c], a);
    ql[t] = fmaxf(a, 0.f) * dc_p_w[t];
  }
  __syncthreads();
  if (t == 0) {
    float a = 0.f;
    for (int d = 0; d < 64; ++d) a += ql[d];
    qdot[blockIdx.x] = a;
  }
}

// ---------------------------------------------------------------------------
// K3: dep_att[e][n][k] = sigmoid(qdot + keydot + b) * (1 - p_att[1+e])
// ---------------------------------------------------------------------------
__global__ __launch_bounds__(256) void k_depatt(
    const float* __restrict__ p_att, const float* __restrict__ keydot,
    const float* __restrict__ qdot, const float* __restrict__ dc_p_b,
    float* __restrict__ dep_att)
{
  int idx = blockIdx.x * 256 + threadIdx.x;
  if (idx >= 6 * NB_ * HW_) return;
  int e = idx / (NB_ * HW_); int r = idx - e * NB_ * HW_;
  int n = r / HW_, k = r - n * HW_;
  float energy = qdot[e * NB_ + n] + keydot[n * HW_ + k] + dc_p_b[0];
  float a = sigmoidf_(energy);
  float hu = p_att[(size_t)((1 + e) * NB_ + n) * HW_ + k];
  dep_att[idx] = a * (1.f - hu);
}

// ---------------------------------------------------------------------------
// K4: rpx[n][d][k] = relu(sum_c dp_proj[d,c]*xp[n,c,k])
// ---------------------------------------------------------------------------
__global__ __launch_bounds__(256) void k_rpx(
    const float* __restrict__ xp, const float* __restrict__ dp_proj,
    float* __restrict__ rpx)
{
  __shared__ float pj[10 * 256];
  int t = threadIdx.x;
  for (int i = t; i < 2560; i += 256) pj[i] = dp_proj[i];
  __syncthreads();
  int p = blockIdx.x * 256 + t;
  if (p >= NB_ * HW_) return;
  int n = p / HW_, k = p - n * HW_;
  float acc[10];
  #pragma unroll
  for (int d = 0; d < 10; ++d) acc[d] = 0.f;
  const float* x = xp + (size_t)n * C_ * HW_ + k;
  for (int c = 0; c < 256; ++c) {
    float v = x[(size_t)c * HW_];
    #pragma unroll
    for (int d = 0; d < 10; ++d) acc[d] = fmaf(pj[d * 256 + c], v, acc[d]);
  }
  #pragma unroll
  for (int d = 0; d < 10; ++d) rpx[(size_t)(n * 10 + d) * HW_ + k] = fmaxf(acc[d], 0.f);
}

// ---------------------------------------------------------------------------
// K5: MFMA implicit-GEMM conv. Block = 64 oc x 128 px (16y x 8x), 4 waves.
// Wave = 32 oc (2 M-frags) x 64 px (4 N-frags), mfma_f32_16x16x32_bf16.
// K-loop: 8 channel chunks x 9 kernel positions (shifted LDS reads).
// att channel (c=0) added as fp32 epilogue. Output: relu -> bf16 h1[oc][px].
// ---------------------------------------------------------------------------
__global__ __launch_bounds__(256) void k_convmma(
    const unsigned short* __restrict__ xbf, const unsigned short* __restrict__ wt,
    const float* __restrict__ w0, const float* __restrict__ dep_att,
    const float* __restrict__ h_att, unsigned short* __restrict__ h1)
{
  int b = blockIdx.x;
  int pxt = b % 18; b /= 18;
  int ocb = b % 4;  b /= 4;
  int n = b % NB_;  int inst = b / NB_;
  int y0 = (pxt / 6) * 16, x0 = (pxt % 6) * 8;

  __shared__ unsigned short xs[180 * 40];  // [halo pos(18y*10x)][40ch pad] bf16
  __shared__ float asf[180];               // att halo fp32
  __shared__ float w0l[64 * 9];

  const float* asrc = (inst < 6) ? dep_att + (size_t)(inst * NB_ + n) * HW_
                    : h_att + (size_t)(((inst == 6) ? 1 : 2) * NB_ + n) * HW_;

  int t = threadIdx.x;
  for (int i = t; i < 180; i += 256) {
    int yy = i / 10, xx = i - yy * 10;
    int gy = y0 + yy - 1, gx = x0 + xx - 1;
    asf[i] = (gy >= 0 && gy < 48 && gx >= 0 && gx < 48) ? asrc[gy * 48 + gx] : 0.f;
  }
  for (int i = t; i < 576; i += 256) {
    int oc = i / 9, pos = i - oc * 9;
    w0l[i] = w0[((size_t)inst * 256 + ocb * 64 + oc) * 9 + pos];
  }

  int w = t >> 6, l = t & 63;
  int wm = w >> 1, wn = w & 1;
  int lr = l & 15, lg = l >> 4;

  f32x4 acc[2][4];
  #pragma unroll
  for (int m = 0; m < 2; ++m)
    #pragma unroll
    for (int nf = 0; nf < 4; ++nf) acc[m][nf] = (f32x4){0.f, 0.f, 0.f, 0.f};

  const unsigned short* wtb =
      wt + ((size_t)inst * 9 * 256 + (size_t)(ocb * 64 + wm * 32)) * 256;
  const unsigned short* xg = xbf + (size_t)n * HW_ * 256;

  for (int chunk = 0; chunk < 8; ++chunk) {
    __syncthreads();
    for (int i = t; i < 720; i += 256) {
      int pos = i >> 2, q = i & 3;
      int yy = pos / 10, xx = pos - yy * 10;
      int gy = y0 + yy - 1, gx = x0 + xx - 1;
      short8 v = (short8){0,0,0,0,0,0,0,0};
      if (gy >= 0 && gy < 48 && gx >= 0 && gx < 48)
        v = *(const short8*)(xg + ((size_t)(gy * 48 + gx)) * 256 + chunk * 32 + q * 8);
      *(short8*)(xs + pos * 40 + q * 8) = v;
    }
    __syncthreads();

    int co = chunk * 32 + lg * 8;
    short8 a0 = *(const short8*)(wtb + (size_t)(lr) * 256 + co);
    short8 a1 = *(const short8*)(wtb + (size_t)(16 + lr) * 256 + co);
    for (int pos = 0; pos < 9; ++pos) {
      short8 na0, na1;
      if (pos < 8) {
        na0 = *(const short8*)(wtb + (size_t)((pos + 1) * 256 + lr) * 256 + co);
        na1 = *(const short8*)(wtb + (size_t)((pos + 1) * 256 + 16 + lr) * 256 + co);
      }
      int kh = pos / 3, kw = pos - kh * 3;
      short8 bfr[4];
      #pragma unroll
      for (int nf = 0; nf < 4; ++nf) {
        int p = wn * 64 + nf * 16 + lr;
        int y = p >> 3, x = p & 7;
        bfr[nf] = *(const short8*)(xs + ((y + kh) * 10 + (x + kw)) * 40 + lg * 8);
      }
      #pragma unroll
      for (int nf = 0; nf < 4; ++nf) {
        acc[0][nf] = __builtin_amdgcn_mfma_f32_16x16x32_bf16(a0, bfr[nf], acc[0][nf], 0, 0, 0);
        acc[1][nf] = __builtin_amdgcn_mfma_f32_16x16x32_bf16(a1, bfr[nf], acc[1][nf], 0, 0, 0);
      }
      a0 = na0; a1 = na1;
    }
  }

  // epilogue: + att-channel conv, relu, store bf16
  size_t h1base = ((size_t)(inst * NB_ + n) * 256) * HW_;
  #pragma unroll
  for (int m = 0; m < 2; ++m) {
    #pragma unroll
    for (int nf = 0; nf < 4; ++nf) {
      int p = wn * 64 + nf * 16 + lr;
      int y = p >> 3, x = p & 7;
      #pragma unroll
      for (int r = 0; r < 4; ++r) {
        int ocl = wm * 32 + m * 16 + lg * 4 + r;
        float v = acc[m][nf][r];
        const float* wr = &w0l[ocl * 9];
        #pragma unroll
        for (int pos = 0; pos < 9; ++pos) {
          int kh = pos / 3, kw = pos - kh * 3;
          v = fmaf(wr[pos], asf[(y + kh) * 10 + (x + kw)], v);
        }
        v = fmaxf(v, 0.f);
        int gk = (y0 + y) * 48 + x0 + x;
        h1[h1base + (size_t)(ocb * 64 + ocl) * HW_ + gk] = f2bf(v);
      }
    }
  }
}

// ---------------------------------------------------------------------------
// K6: heads: d-dot over 256 oc of h1, +bias, raw outputs + softmax
// grid = inst(8) x n(2) x pxchunk(9), 256 px/block
// ---------------------------------------------------------------------------
__global__ __launch_bounds__(256) void k_heads(
    const unsigned short* __restrict__ h1,
    const float* __restrict__ ctx_w2, const float* __restrict__ du_a2,
    const float* __restrict__ dl_a2,
    const float* __restrict__ ctx_b2, const float* __restrict__ du_a2b,
    const float* __restrict__ dl_a2b,
    float* __restrict__ out_fdep, float* __restrict__ out_du, float* __restrict__ out_dl,
    float* __restrict__ att_sm, float* __restrict__ da_u, float* __restrict__ da_l)
{
  __shared__ float w2l[5 * 256];
  int bid = blockIdx.x;
  int pc = bid % 9; bid /= 9;
  int n = bid % NB_; int inst = bid / NB_;
  int nd = (inst < 6) ? 5 : (inst == 6 ? 4 : 2);
  const float* w2 = (inst < 6) ? ctx_w2 + (size_t)inst * 5 * 256
                               : (inst == 6 ? du_a2 : dl_a2);
  int t = threadIdx.x;
  for (int i = t; i < 1280; i += 256) w2l[i] = (i < nd * 256) ? w2[i] : 0.f;
  __syncthreads();
  int k = pc * 256 + t;
  const unsigned short* hb = h1 + ((size_t)(inst * NB_ + n) * 256) * HW_ + k;
  float s[5] = {0.f, 0.f, 0.f, 0.f, 0.f};
  for (int oc = 0; oc < 256; ++oc) {
    float hv = bf2f(hb[(size_t)oc * HW_]);
    #pragma unroll
    for (int d = 0; d < 5; ++d) s[d] = fmaf(w2l[d * 256 + oc], hv, s[d]);
  }
  float v[5];
  float mx = -1e30f;
  for (int d = 0; d < nd; ++d) {
    float bsum = (inst < 6) ? ctx_b2[inst * 5 + d] : (inst == 6 ? du_a2b[d] : dl_a2b[d]);
    float val = s[d] + bsum;
    v[d] = val;
    mx = fmaxf(mx, val);
    if (inst < 6)       out_fdep[((size_t)(inst * NB_ + n) * 5 + d) * HW_ + k] = val;
    else if (inst == 6) out_du[((size_t)n * 4 + d) * HW_ + k] = val;
    else                out_dl[((size_t)n * 2 + d) * HW_ + k] = val;
  }
  float ssum = 0.f;
  for (int d = 0; d < nd; ++d) { v[d] = expf(v[d] - mx); ssum += v[d]; }
  float is = 1.f / ssum;
  for (int d = 0; d < nd; ++d) {
    float sm = v[d] * is;
    if (inst < 6)       att_sm[((size_t)(inst * NB_ + n) * 5 + d) * HW_ + k] = sm;
    else if (inst == 6) da_u[((size_t)n * 4 + d) * HW_ + k] = sm;
    else                da_l[((size_t)n * 2 + d) * HW_ + k] = sm;
  }
}

// ---------------------------------------------------------------------------
// K7: dep messages + segment_sum -> xpp[v][n][10][HW]
// ---------------------------------------------------------------------------
__global__ __launch_bounds__(256) void k_msgs(
    const float* __restrict__ p_nodes, const float* __restrict__ att_sm,
    const float* __restrict__ dep_att, const float* __restrict__ rpx,
    const float* __restrict__ dp_r1, const float* __restrict__ dp_r2,
    const float* __restrict__ dp_r2b, float* __restrict__ xpp)
{
  int b = blockIdx.x;
  int tile = b % 9; b /= 9;
  int n = b % NB_;  int v = b / NB_;
  int ty0 = (tile / 3) * 16, tx0 = (tile % 3) * 16;
  __shared__ float xt[20][18][20];
  __shared__ float wl[1800];
  __shared__ float w2l[100];
  __shared__ float b2l[10];
  int t = threadIdx.x;
  for (int i = t; i < 1800; i += 256) wl[i] = dp_r1[i];
  for (int i = t; i < 100; i += 256) w2l[i] = dp_r2[i];
  if (t < 10) b2l[t] = dp_r2b[t];
  for (int i = t; i < 10 * 324; i += 256) {
    int d = i / 324; int rr = (i % 324) / 18; int cc = i % 18;
    int gy = ty0 + rr - 1, gx = tx0 + cc - 1;
    float val = 0.f;
    if (gy >= 0 && gy < 48 && gx >= 0 && gx < 48)
      val = p_nodes[((size_t)(v * NB_ + n) * 10 + d) * HW_ + gy * 48 + gx];
    xt[10 + d][rr][cc] = val;
  }
  int rr = t >> 4, cc = t & 15;
  int k = (ty0 + rr) * 48 + tx0 + cc;
  float msum[10];
  #pragma unroll
  for (int d = 0; d < 10; ++d) msum[d] = 0.f;

  for (int u = 0; u < 6; ++u) {
    if (u == v) continue;
    int ce = (v < u) ? v : v - 1;
    __syncthreads();
    const float* asrc = att_sm + ((size_t)(u * NB_ + n) * 5 + ce) * HW_;
    const float* dsrc = dep_att + (size_t)(u * NB_ + n) * HW_;
    for (int i = t; i < 10 * 324; i += 256) {
      int d = i / 324; int r2 = (i % 324) / 18; int c2 = i % 18;
      int gy = ty0 + r2 - 1, gx = tx0 + c2 - 1;
      float val = 0.f;
      if (gy >= 0 && gy < 48 && gx >= 0 && gx < 48) {
        int kk = gy * 48 + gx;
        val = asrc[kk] * dsrc[kk] * rpx[((size_t)n * 10 + d) * HW_ + kk];
      }
      xt[d][r2][c2] = val;
    }
    __syncthreads();
    float y[10];
    #pragma unroll
    for (int d = 0; d < 10; ++d) y[d] = 0.f;
    for (int ic = 0; ic < 20; ++ic)
      #pragma unroll
      for (int kh = 0; kh < 3; ++kh)
        #pragma unroll
        for (int kw = 0; kw < 3; ++kw) {
          float xv = xt[ic][rr + kh][cc + kw];
          #pragma unroll
          for (int d = 0; d < 10; ++d)
            y[d] = fmaf(wl[(d * 20 + ic) * 9 + kh * 3 + kw], xv, y[d]);
        }
    #pragma unroll
    for (int d = 0; d < 10; ++d) y[d] = fmaxf(y[d], 0.f);
    #pragma unroll
    for (int d = 0; d < 10; ++d) {
      float s = b2l[d];
      #pragma unroll
      for (int j = 0; j < 10; ++j) s = fmaf(w2l[d * 10 + j], y[j], s);
      msum[d] += sigmoidf_(s);
    }
  }
  #pragma unroll
  for (int d = 0; d < 10; ++d)
    xpp[((size_t)(v * NB_ + n) * 10 + d) * HW_ + k] = msum[d];
}

// ---------------------------------------------------------------------------
// K8: du/dl parts conv + combine with alpha*xpp + GRU  (nodes 1..6)
// ---------------------------------------------------------------------------
__global__ __launch_bounds__(256) void k_parts_gru(
    const float* __restrict__ h_nodes, const float* __restrict__ p_nodes,
    const float* __restrict__ h_att,
    const float* __restrict__ da_u, const float* __restrict__ da_l,
    const float* __restrict__ du_r1, const float* __restrict__ du_r2,
    const float* __restrict__ dl_r1, const float* __restrict__ dl_r2,
    const float* __restrict__ xpp, const float* __restrict__ alpha,
    const float* __restrict__ gru_gw, const float* __restrict__ gru_gb,
    const float* __restrict__ gru_cw, float* __restrict__ p_new)
{
  int b = blockIdx.x;
  int tile = b % 9; b /= 9;
  int n = b % NB_;  int vp = b / NB_ + 1;
  int ty0 = (tile / 3) * 16, tx0 = (tile % 3) * 16;
  bool isU = (vp <= 4);
  int j = isU ? vp - 1 : vp - 5;
  const float* parent = h_nodes + ((size_t)((isU ? 1 : 2) * NB_ + n) * 10) * HW_;
  const float* patt   = h_att + (size_t)((isU ? 1 : 2) * NB_ + n) * HW_;
  const float* da     = isU ? (da_u + ((size_t)n * 4 + j) * HW_) : (da_l + ((size_t)n * 2 + j) * HW_);
  const float* child  = p_nodes + (size_t)(vp * NB_ + n) * 10 * HW_;
  const float* r1 = isU ? du_r1 : dl_r1;
  const float* r2 = isU ? du_r2 : dl_r2;

  __shared__ float xt[20][18][20];
  __shared__ float wl[1800];
  __shared__ float w2l[100];
  int t = threadIdx.x;
  for (int i = t; i < 1800; i += 256) wl[i] = r1[i];
  for (int i = t; i < 100; i += 256) w2l[i] = r2[i];
  for (int i = t; i < 20 * 324; i += 256) {
    int d = i / 324; int rr = (i % 324) / 18; int cc = i % 18;
    int gy = ty0 + rr - 1, gx = tx0 + cc - 1;
    float val = 0.f;
    if (gy >= 0 && gy < 48 && gx >= 0 && gx < 48) {
      int kk = gy * 48 + gx;
      val = (d < 10) ? parent[(size_t)d * HW_ + kk] * da[kk] * patt[kk]
                     : child[(size_t)(d - 10) * HW_ + kk];
    }
    xt[d][rr][cc] = val;
  }
  __syncthreads();
  int rr = t >> 4, cc = t & 15;
  int k = (ty0 + rr) * 48 + tx0 + cc;
  float y[10];
  #pragma unroll
  for (int d = 0; d < 10; ++d) y[d] = 0.f;
  for (int ic = 0; ic < 20; ++ic)
    #pragma unroll
    for (int kh = 0; kh < 3; ++kh)
      #pragma unroll
      for (int kw = 0; kw < 3; ++kw) {
        float xv = xt[ic][rr + kh][cc + kw];
        #pragma unroll
        for (int d = 0; d < 10; ++d)
          y[d] = fmaf(wl[(d * 20 + ic) * 9 + kh * 3 + kw], xv, y[d]);
      }
  float yr[10];
  #pragma unroll
  for (int d = 0; d < 10; ++d) yr[d] = fmaxf(y[d], 0.f);

  float al = alpha[0];
  float x[10], h[10];
  #pragma unroll
  for (int d = 0; d < 10; ++d) {
    float s = 0.f;
    #pragma unroll
    for (int jj = 0; jj < 10; ++jj) s = fmaf(w2l[d * 10 + jj], yr[jj], s);
    float parts = fmaxf(s, 0.f);
    x[d] = parts + al * xpp[((size_t)((vp - 1) * NB_ + n) * 10 + d) * HW_ + k];
    h[d] = p_nodes[((size_t)(vp * NB_ + n) * 10 + d) * HW_ + k];
  }
  const float* gw = gru_gw + (size_t)vp * 40;
  const float* gb = gru_gb + (size_t)vp * 2;
  const float* cw = gru_cw + (size_t)vp * 200;
  float g0 = gb[0], g1 = gb[1];
  #pragma unroll
  for (int d = 0; d < 10; ++d) {
    g0 = fmaf(gw[d], x[d], fmaf(gw[10 + d], h[d], g0));
    g1 = fmaf(gw[20 + d], x[d], fmaf(gw[30 + d], h[d], g1));
  }
  float rg = sigmoidf_(g0);
  float ug = sigmoidf_(g1);
  #pragma unroll
  for (int d = 0; d < 10; ++d) {
    float s = 0.f;
    const float* cr = cw + d * 20;
    #pragma unroll
    for (int jj = 0; jj < 10; ++jj)
      s = fmaf(cr[jj], x[jj], fmaf(cr[10 + jj], rg * h[jj], s));
    float cn = fmaxf(s, 0.f);
    p_new[((size_t)(vp * NB_ + n) * 10 + d) * HW_ + k] = (1.f - ug) * h[d] + ug * cn;
  }
}

// ---------------------------------------------------------------------------
// K9: GRU for node 0
// ---------------------------------------------------------------------------
__global__ __launch_bounds__(256) void k_gru0(
    const float* __restrict__ h_nodes, const float* __restrict__ p_nodes,
    const float* __restrict__ gru_gw, const float* __restrict__ gru_gb,
    const float* __restrict__ gru_cw, float* __restrict__ p_new)
{
  int idx = blockIdx.x * 256 + threadIdx.x;
  if (idx >= NB_ * HW_) return;
  int n = idx / HW_, k = idx - n * HW_;
  float x[10], h[10];
  #pragma unroll
  for (int d = 0; d < 10; ++d) {
    x[d] = h_nodes[((size_t)n * 10 + d) * HW_ + k];
    h[d] = p_nodes[((size_t)n * 10 + d) * HW_ + k];
  }
  float g0 = gru_gb[0], g1 = gru_gb[1];
  #pragma unroll
  for (int d = 0; d < 10; ++d) {
    g0 = fmaf(gru_gw[d], x[d], fmaf(gru_gw[10 + d], h[d], g0));
    g1 = fmaf(gru_gw[20 + d], x[d], fmaf(gru_gw[30 + d], h[d], g1));
  }
  float rg = sigmoidf_(g0);
  float ug = sigmoidf_(g1);
  #pragma unroll
  for (int d = 0; d < 10; ++d) {
    float s = 0.f;
    const float* cr = gru_cw + d * 20;
    #pragma unroll
    for (int jj = 0; jj < 10; ++jj)
      s = fmaf(cr[jj], x[jj], fmaf(cr[10 + jj], rg * h[jj], s));
    float cn = fmaxf(s, 0.f);
    p_new[((size_t)n * 10 + d) * HW_ + k] = (1.f - ug) * h[d] + ug * cn;
  }
}

// ---------------------------------------------------------------------------
extern "C" void kernel_launch(void* const* d_in, const int* in_sizes, int n_in,
                              void* d_out, int out_size, void* d_ws, size_t ws_size,
                              hipStream_t stream) {
  (void)in_sizes; (void)n_in; (void)out_size; (void)ws_size;
  const float* h_nodes = (const float*)d_in[1];
  const float* p_nodes = (const float*)d_in[2];
  const float* xp      = (const float*)d_in[3];
  const float* h_att   = (const float*)d_in[4];
  const float* p_att   = (const float*)d_in[5];
  const float* dc_q_w  = (const float*)d_in[6];
  const float* dc_q_b  = (const float*)d_in[7];
  const float* dc_k_w  = (const float*)d_in[8];
  const float* dc_k_b  = (const float*)d_in[9];
  const float* dc_p_w  = (const float*)d_in[10];
  const float* dc_p_b  = (const float*)d_in[11];
  const float* ctx_w1  = (const float*)d_in[12];
  const float* ctx_w2  = (const float*)d_in[13];
  const float* ctx_b2  = (const float*)d_in[14];
  const float* du_a1   = (const float*)d_in[15];
  const float* du_a2   = (const float*)d_in[16];
  const float* du_a2b  = (const float*)d_in[17];
  const float* du_r1   = (const float*)d_in[18];
  const float* du_r2   = (const float*)d_in[19];
  const float* dl_a1   = (const float*)d_in[20];
  const float* dl_a2   = (const float*)d_in[21];
  const float* dl_a2b  = (const float*)d_in[22];
  const float* dl_r1   = (const float*)d_in[23];
  const float* dl_r2   = (const float*)d_in[24];
  const float* dp_proj = (const float*)d_in[25];
  const float* dp_r1   = (const float*)d_in[26];
  const float* dp_r2   = (const float*)d_in[27];
  const float* dp_r2b  = (const float*)d_in[28];
  const float* gru_gw  = (const float*)d_in[29];
  const float* gru_gb  = (const float*)d_in[30];
  const float* gru_cw  = (const float*)d_in[31];
  const float* alpha   = (const float*)d_in[32];

  float* ws = (float*)d_ws;
  float* keydot  = ws;                 // 4608
  float* qdot    = ws + 4608;          // 16
  float* dep_att = ws + 4624;          // 27648
  float* rpx     = ws + 32272;         // 46080
  float* att_sm  = ws + 78352;         // 138240
  float* da_u    = ws + 216592;        // 18432
  float* da_l    = ws + 235024;        // 9216
  float* xpp     = ws + 244240;        // 276480
  float* w0      = ws + 520720;        // 18432 -> floats end at 539152
  unsigned short* us = (unsigned short*)(ws + 539152);
  unsigned short* xbf = us;                       // 1,179,648
  unsigned short* wt  = us + 1179648;             // 4,718,592
  unsigned short* h1  = us + 5898240;             // 9,437,184  (total ~33 MB)

  float* out      = (float*)d_out;
  float* out_pnew = out;               // 322560
  float* out_du   = out + 322560;      // 18432
  float* out_dl   = out + 340992;      // 9216
  float* out_fdep = out + 350208;      // 138240

  k_xbf<<<72, 256, 0, stream>>>(xp, xbf);
  k_wbf<<<2048, 256, 0, stream>>>(ctx_w1, du_a1, dl_a1, wt, w0);
  k_keydot<<<288, 256, 0, stream>>>(xbf, dc_k_w, dc_k_b, dc_p_w, keydot);
  k_ctxq<<<12, 256, 0, stream>>>(xp, p_att, dc_q_w, dc_q_b, dc_p_w, qdot);
  k_depatt<<<108, 256, 0, stream>>>(p_att, keydot, qdot, dc_p_b, dep_att);
  k_rpx<<<18, 256, 0, stream>>>(xp, dp_proj, rpx);
  k_convmma<<<1152, 256, 0, stream>>>(xbf, wt, w0, dep_att, h_att, h1);
  k_heads<<<144, 256, 0, stream>>>(h1, ctx_w2, du_a2, dl_a2, ctx_b2, du_a2b, dl_a2b,
                                   out_fdep, out_du, out_dl, att_sm, da_u, da_l);
  k_msgs<<<108, 256, 0, stream>>>(p_nodes, att_sm, dep_att, rpx,
                                  dp_r1, dp_r2, dp_r2b, xpp);
  k_parts_gru<<<108, 256, 0, stream>>>(h_nodes, p_nodes, h_att, da_u, da_l,
                                       du_r1, du_r2, dl_r1, dl_r2, xpp, alpha,
                                       gru_gw, gru_gb, gru_cw, out_pnew);
  k_gru0<<<18, 256, 0, stream>>>(h_nodes, p_nodes, gru_gw, gru_gb, gru_cw, out_pnew);
}

// Round 3
// 465.847 us; speedup vs baseline: 5.2736x; 2.0490x over previous
//
#include <hip/hip_runtime.h>
#include <math.h>

// Problem constants: N=2, C=256, H=W=48, HID=10, P=7
constexpr int NB_ = 2;
constexpr int C_  = 256;
constexpr int HW_ = 2304;   // 48*48

typedef float f32x4 __attribute__((ext_vector_type(4)));
typedef short short8 __attribute__((ext_vector_type(8)));

__device__ __forceinline__ float coordval(int c, int k) {
  int y = k / 48, x = k - y * 48;
  switch (c) {
    case 0: return x * (1.f/24.f) - 1.f;
    case 1: return y * (1.f/24.f) - 1.f;
    case 2: return (x + 1) * (1.f/24.f) - 1.f;
    case 3: return (y + 1) * (1.f/24.f) - 1.f;
    case 4: return (x + 0.5f) * (1.f/24.f) - 1.f;
    case 5: return (y + 0.5f) * (1.f/24.f) - 1.f;
    default: return 1.f/48.f;
  }
}

__device__ __forceinline__ float sigmoidf_(float x) { return 1.f / (1.f + expf(-x)); }
__device__ __forceinline__ unsigned short f2bf(float f) {
  unsigned int u = __float_as_uint(f);
  unsigned int r = (u + 0x7FFFu + ((u >> 16) & 1u)) >> 16;
  return (unsigned short)r;
}
__device__ __forceinline__ float bf2f(unsigned short h) {
  return __uint_as_float(((unsigned int)h) << 16);
}

// ---------------------------------------------------------------------------
// P1: xbf[n][y][x][c] = bf16(xp[n][c][y*48+x])   (NHWC bf16)
// ---------------------------------------------------------------------------
__global__ __launch_bounds__(256) void k_xbf(
    const float* __restrict__ xp, unsigned short* __restrict__ xbf)
{
  __shared__ float xt[64][65];
  int t = threadIdx.x;
  int px0 = blockIdx.x * 64;
  int n = px0 / HW_, k0 = px0 - n * HW_;
  for (int cb = 0; cb < 4; ++cb) {
    __syncthreads();
    for (int i = t; i < 4096; i += 256) {
      int cl = i >> 6, pxl = i & 63;
      xt[cl][pxl] = xp[((size_t)(n * C_ + cb * 64 + cl)) * HW_ + k0 + pxl];
    }
    __syncthreads();
    for (int i = t; i < 4096; i += 256) {
      int pxl = i >> 6, cl = i & 63;
      xbf[((size_t)(n * HW_ + k0 + pxl)) * 256 + cb * 64 + cl] = f2bf(xt[cl][pxl]);
    }
  }
}

// ---------------------------------------------------------------------------
// P2: weight transform.
// ---------------------------------------------------------------------------
__global__ __launch_bounds__(256) void k_wbf(
    const float* __restrict__ ctx_w1, const float* __restrict__ du_a1,
    const float* __restrict__ dl_a1,
    unsigned short* __restrict__ wt, float* __restrict__ w0)
{
  int inst = blockIdx.x >> 8, oc = blockIdx.x & 255;
  const float* src = (inst < 6) ? (ctx_w1 + (size_t)inst * 256 * 2313)
                   : (inst == 6 ? du_a1 : dl_a1);
  src += (size_t)oc * 2313;
  int t = threadIdx.x;
  for (int i = t; i < 2304; i += 256) {
    int pos = i >> 8, c = i & 255;
    float v = src[(size_t)(c + 1) * 9 + pos];
    wt[((size_t)(inst * 9 + pos) * 256 + oc) * 256 + c] = f2bf(v);
  }
  if (t < 9) w0[((size_t)inst * 256 + oc) * 9 + t] = src[t];
}

// ---------------------------------------------------------------------------
// K1: keydot
// ---------------------------------------------------------------------------
__global__ __launch_bounds__(256) void k_keydot(
    const unsigned short* __restrict__ xbf, const float* __restrict__ dc_k_w,
    const float* __restrict__ dc_k_b, const float* __restrict__ dc_p_w,
    float* __restrict__ keydot)
{
  __shared__ unsigned short wl[264 * 64];   // [c][d] bf16
  __shared__ float xl[16][265];
  __shared__ float wkl[64], bl[64];
  int t = threadIdx.x;
  for (int i = t; i < 64 * 264; i += 256) {
    int d = i / 264, c = i - d * 264;
    wl[c * 64 + d] = f2bf(dc_k_w[i]);
  }
  if (t < 64) { wkl[t] = dc_p_w[64 + t]; bl[t] = dc_k_b[t]; }
  int p0 = blockIdx.x * 16;
  for (int i = t; i < 16 * 264; i += 256) {
    int pl = i / 264, c = i - pl * 264;
    int p = p0 + pl, n = p / HW_, k = p - n * HW_;
    xl[pl][c] = (c < 256) ? bf2f(xbf[((size_t)(n * HW_ + k)) * 256 + c])
                          : coordval(c - 256, k);
  }
  __syncthreads();
  int d = t & 63, wg = t >> 6;
  for (int q = 0; q < 4; ++q) {
    int pl = wg * 4 + q;
    float a = bl[d];
    for (int c = 0; c < 264; ++c) a = fmaf(bf2f(wl[c * 64 + d]), xl[pl][c], a);
    a = fmaxf(a, 0.f) * wkl[d];
    #pragma unroll
    for (int off = 32; off > 0; off >>= 1) a += __shfl_down(a, off, 64);
    if (d == 0) keydot[p0 + pl] = a;
  }
}

// ---------------------------------------------------------------------------
// K2a: na[pair][k] = softmax over HW of p_att[1+i][n]   (pair = i*NB+n)
// ---------------------------------------------------------------------------
__global__ __launch_bounds__(256) void k_sm(
    const float* __restrict__ p_att, float* __restrict__ na_ws)
{
  __shared__ float red[16];
  int t = threadIdx.x;
  const float* att = p_att + (size_t)(NB_ + blockIdx.x) * HW_;
  float* na = na_ws + (size_t)blockIdx.x * HW_;

  float m = -1e30f;
  for (int k = t; k < HW_; k += 256) m = fmaxf(m, att[k]);
  #pragma unroll
  for (int off = 32; off > 0; off >>= 1) m = fmaxf(m, __shfl_down(m, off, 64));
  if ((t & 63) == 0) red[t >> 6] = m;
  __syncthreads();
  if (t == 0) { float mm = red[0]; for (int w = 1; w < 4; ++w) mm = fmaxf(mm, red[w]); red[0] = mm; }
  __syncthreads();
  m = red[0];
  float s = 0.f;
  for (int k = t; k < HW_; k += 256) s += expf(att[k] - m);
  #pragma unroll
  for (int off = 32; off > 0; off >>= 1) s += __shfl_down(s, off, 64);
  if ((t & 63) == 0) red[8 + (t >> 6)] = s;
  __syncthreads();
  if (t == 0) { float ss = 0; for (int w = 0; w < 4; ++w) ss += red[8 + w]; red[8] = ss; }
  __syncthreads();
  float inv = 1.f / red[8];
  for (int k = t; k < HW_; k += 256) na[k] = expf(att[k] - m) * inv;
}

// ---------------------------------------------------------------------------
// K2b: hu[pair][c] = sum_k xp[n,c,k] * na[pair][k]
// grid = pair(12) x cb(16), wave-per-channel coalesced reduce
// ---------------------------------------------------------------------------
__global__ __launch_bounds__(256) void k_huc(
    const float* __restrict__ xp, const float* __restrict__ na_ws,
    float* __restrict__ hu_ws)
{
  __shared__ float na[HW_];
  int b = blockIdx.x;
  int cb = b & 15; int pair = b >> 4;
  int n = pair % NB_;
  int t = threadIdx.x;
  const float* nag = na_ws + (size_t)pair * HW_;
  for (int k = t; k < HW_; k += 256) na[k] = nag[k];
  __syncthreads();
  int wv = t >> 6, l = t & 63;
  #pragma unroll
  for (int cq = 0; cq < 4; ++cq) {
    int c = cb * 16 + wv * 4 + cq;
    const float* x = xp + (size_t)(n * C_ + c) * HW_;
    float a = 0.f;
    for (int k = l; k < HW_; k += 64) a = fmaf(x[k], na[k], a);
    #pragma unroll
    for (int off = 32; off > 0; off >>= 1) a += __shfl_down(a, off, 64);
    if (l == 0) hu_ws[(size_t)pair * 256 + c] = a;
  }
}

// ---------------------------------------------------------------------------
// K2c: co coords + q + qdot per pair   (12 blocks)
// ---------------------------------------------------------------------------
__global__ __launch_bounds__(256) void k_qdot(
    const float* __restrict__ na_ws, const float* __restrict__ hu_ws,
    const float* __restrict__ dc_q_w, const float* __restrict__ dc_q_b,
    const float* __restrict__ dc_p_w, float* __restrict__ qdot)
{
  __shared__ float na[HW_];
  __shared__ float co[8];
  __shared__ float hu[256];
  __shared__ float ql[64];
  int t = threadIdx.x;
  int pair = blockIdx.x;
  const float* nag = na_ws + (size_t)pair * HW_;
  for (int k = t; k < HW_; k += 256) na[k] = nag[k];
  hu[t] = hu_ws[(size_t)pair * 256 + t];
  __syncthreads();
  int wv = t >> 6, l = t & 63;
  #pragma unroll
  for (int q = 0; q < 2; ++q) {
    int cc = wv * 2 + q;
    float a = 0.f;
    for (int k = l; k < HW_; k += 64) a = fmaf(coordval(cc, k), na[k], a);
    #pragma unroll
    for (int off = 32; off > 0; off >>= 1) a += __shfl_down(a, off, 64);
    if (l == 0) co[cc] = a;
  }
  __syncthreads();
  if (t < 64) {
    float a = dc_q_b[t];
    const float* wr = dc_q_w + (size_t)t * 264;
    for (int c = 0; c < 256; ++c) a = fmaf(wr[c], hu[c], a);
    #pragma unroll
    for (int c = 0; c < 8; ++c) a = fmaf(wr[256 + c], co[c], a);
    ql[t] = fmaxf(a, 0.f) * dc_p_w[t];
  }
  __syncthreads();
  if (t == 0) {
    float a = 0.f;
    for (int d = 0; d < 64; ++d) a += ql[d];
    qdot[pair] = a;
  }
}

// ---------------------------------------------------------------------------
// K3: dep_att[e][n][k] = sigmoid(qdot + keydot + b) * (1 - p_att[1+e])
// ---------------------------------------------------------------------------
__global__ __launch_bounds__(256) void k_depatt(
    const float* __restrict__ p_att, const float* __restrict__ keydot,
    const float* __restrict__ qdot, const float* __restrict__ dc_p_b,
    float* __restrict__ dep_att)
{
  int idx = blockIdx.x * 256 + threadIdx.x;
  if (idx >= 6 * NB_ * HW_) return;
  int e = idx / (NB_ * HW_); int r = idx - e * NB_ * HW_;
  int n = r / HW_, k = r - n * HW_;
  float energy = qdot[e * NB_ + n] + keydot[n * HW_ + k] + dc_p_b[0];
  float a = sigmoidf_(energy);
  float hu = p_att[(size_t)((1 + e) * NB_ + n) * HW_ + k];
  dep_att[idx] = a * (1.f - hu);
}

// ---------------------------------------------------------------------------
// K4: rpx[n][d][k] = relu(sum_c dp_proj[d,c]*xp[n,c,k])
// ---------------------------------------------------------------------------
__global__ __launch_bounds__(256) void k_rpx(
    const float* __restrict__ xp, const float* __restrict__ dp_proj,
    float* __restrict__ rpx)
{
  __shared__ float pj[10 * 256];
  int t = threadIdx.x;
  for (int i = t; i < 2560; i += 256) pj[i] = dp_proj[i];
  __syncthreads();
  int p = blockIdx.x * 256 + t;
  if (p >= NB_ * HW_) return;
  int n = p / HW_, k = p - n * HW_;
  float acc[10];
  #pragma unroll
  for (int d = 0; d < 10; ++d) acc[d] = 0.f;
  const float* x = xp + (size_t)n * C_ * HW_ + k;
  for (int c = 0; c < 256; ++c) {
    float v = x[(size_t)c * HW_];
    #pragma unroll
    for (int d = 0; d < 10; ++d) acc[d] = fmaf(pj[d * 256 + c], v, acc[d]);
  }
  #pragma unroll
  for (int d = 0; d < 10; ++d) rpx[(size_t)(n * 10 + d) * HW_ + k] = fmaxf(acc[d], 0.f);
}

// ---------------------------------------------------------------------------
// K5: MFMA implicit-GEMM conv (unchanged from R2)
// ---------------------------------------------------------------------------
__global__ __launch_bounds__(256) void k_convmma(
    const unsigned short* __restrict__ xbf, const unsigned short* __restrict__ wt,
    const float* __restrict__ w0, const float* __restrict__ dep_att,
    const float* __restrict__ h_att, unsigned short* __restrict__ h1)
{
  int b = blockIdx.x;
  int pxt = b % 18; b /= 18;
  int ocb = b % 4;  b /= 4;
  int n = b % NB_;  int inst = b / NB_;
  int y0 = (pxt / 6) * 16, x0 = (pxt % 6) * 8;

  __shared__ unsigned short xs[180 * 40];
  __shared__ float asf[180];
  __shared__ float w0l[64 * 9];

  const float* asrc = (inst < 6) ? dep_att + (size_t)(inst * NB_ + n) * HW_
                    : h_att + (size_t)(((inst == 6) ? 1 : 2) * NB_ + n) * HW_;

  int t = threadIdx.x;
  for (int i = t; i < 180; i += 256) {
    int yy = i / 10, xx = i - yy * 10;
    int gy = y0 + yy - 1, gx = x0 + xx - 1;
    asf[i] = (gy >= 0 && gy < 48 && gx >= 0 && gx < 48) ? asrc[gy * 48 + gx] : 0.f;
  }
  for (int i = t; i < 576; i += 256) {
    int oc = i / 9, pos = i - oc * 9;
    w0l[i] = w0[((size_t)inst * 256 + ocb * 64 + oc) * 9 + pos];
  }

  int w = t >> 6, l = t & 63;
  int wm = w >> 1, wn = w & 1;
  int lr = l & 15, lg = l >> 4;

  f32x4 acc[2][4];
  #pragma unroll
  for (int m = 0; m < 2; ++m)
    #pragma unroll
    for (int nf = 0; nf < 4; ++nf) acc[m][nf] = (f32x4){0.f, 0.f, 0.f, 0.f};

  const unsigned short* wtb =
      wt + ((size_t)inst * 9 * 256 + (size_t)(ocb * 64 + wm * 32)) * 256;
  const unsigned short* xg = xbf + (size_t)n * HW_ * 256;

  for (int chunk = 0; chunk < 8; ++chunk) {
    __syncthreads();
    for (int i = t; i < 720; i += 256) {
      int pos = i >> 2, q = i & 3;
      int yy = pos / 10, xx = pos - yy * 10;
      int gy = y0 + yy - 1, gx = x0 + xx - 1;
      short8 v = (short8){0,0,0,0,0,0,0,0};
      if (gy >= 0 && gy < 48 && gx >= 0 && gx < 48)
        v = *(const short8*)(xg + ((size_t)(gy * 48 + gx)) * 256 + chunk * 32 + q * 8);
      *(short8*)(xs + pos * 40 + q * 8) = v;
    }
    __syncthreads();

    int co = chunk * 32 + lg * 8;
    short8 a0 = *(const short8*)(wtb + (size_t)(lr) * 256 + co);
    short8 a1 = *(const short8*)(wtb + (size_t)(16 + lr) * 256 + co);
    for (int pos = 0; pos < 9; ++pos) {
      short8 na0, na1;
      if (pos < 8) {
        na0 = *(const short8*)(wtb + (size_t)((pos + 1) * 256 + lr) * 256 + co);
        na1 = *(const short8*)(wtb + (size_t)((pos + 1) * 256 + 16 + lr) * 256 + co);
      }
      int kh = pos / 3, kw = pos - kh * 3;
      short8 bfr[4];
      #pragma unroll
      for (int nf = 0; nf < 4; ++nf) {
        int p = wn * 64 + nf * 16 + lr;
        int y = p >> 3, x = p & 7;
        bfr[nf] = *(const short8*)(xs + ((y + kh) * 10 + (x + kw)) * 40 + lg * 8);
      }
      #pragma unroll
      for (int nf = 0; nf < 4; ++nf) {
        acc[0][nf] = __builtin_amdgcn_mfma_f32_16x16x32_bf16(a0, bfr[nf], acc[0][nf], 0, 0, 0);
        acc[1][nf] = __builtin_amdgcn_mfma_f32_16x16x32_bf16(a1, bfr[nf], acc[1][nf], 0, 0, 0);
      }
      a0 = na0; a1 = na1;
    }
  }

  size_t h1base = ((size_t)(inst * NB_ + n) * 256) * HW_;
  #pragma unroll
  for (int m = 0; m < 2; ++m) {
    #pragma unroll
    for (int nf = 0; nf < 4; ++nf) {
      int p = wn * 64 + nf * 16 + lr;
      int y = p >> 3, x = p & 7;
      #pragma unroll
      for (int r = 0; r < 4; ++r) {
        int ocl = wm * 32 + m * 16 + lg * 4 + r;
        float v = acc[m][nf][r];
        const float* wr = &w0l[ocl * 9];
        #pragma unroll
        for (int pos = 0; pos < 9; ++pos) {
          int kh = pos / 3, kw = pos - kh * 3;
          v = fmaf(wr[pos], asf[(y + kh) * 10 + (x + kw)], v);
        }
        v = fmaxf(v, 0.f);
        int gk = (y0 + y) * 48 + x0 + x;
        h1[h1base + (size_t)(ocb * 64 + ocl) * HW_ + gk] = f2bf(v);
      }
    }
  }
}

// ---------------------------------------------------------------------------
// K6: heads
// ---------------------------------------------------------------------------
__global__ __launch_bounds__(256) void k_heads(
    const unsigned short* __restrict__ h1,
    const float* __restrict__ ctx_w2, const float* __restrict__ du_a2,
    const float* __restrict__ dl_a2,
    const float* __restrict__ ctx_b2, const float* __restrict__ du_a2b,
    const float* __restrict__ dl_a2b,
    float* __restrict__ out_fdep, float* __restrict__ out_du, float* __restrict__ out_dl,
    float* __restrict__ att_sm, float* __restrict__ da_u, float* __restrict__ da_l)
{
  __shared__ float w2l[5 * 256];
  int bid = blockIdx.x;
  int pc = bid % 9; bid /= 9;
  int n = bid % NB_; int inst = bid / NB_;
  int nd = (inst < 6) ? 5 : (inst == 6 ? 4 : 2);
  const float* w2 = (inst < 6) ? ctx_w2 + (size_t)inst * 5 * 256
                               : (inst == 6 ? du_a2 : dl_a2);
  int t = threadIdx.x;
  for (int i = t; i < 1280; i += 256) w2l[i] = (i < nd * 256) ? w2[i] : 0.f;
  __syncthreads();
  int k = pc * 256 + t;
  const unsigned short* hb = h1 + ((size_t)(inst * NB_ + n) * 256) * HW_ + k;
  float s[5] = {0.f, 0.f, 0.f, 0.f, 0.f};
  for (int oc = 0; oc < 256; ++oc) {
    float hv = bf2f(hb[(size_t)oc * HW_]);
    #pragma unroll
    for (int d = 0; d < 5; ++d) s[d] = fmaf(w2l[d * 256 + oc], hv, s[d]);
  }
  float v[5];
  float mx = -1e30f;
  for (int d = 0; d < nd; ++d) {
    float bsum = (inst < 6) ? ctx_b2[inst * 5 + d] : (inst == 6 ? du_a2b[d] : dl_a2b[d]);
    float val = s[d] + bsum;
    v[d] = val;
    mx = fmaxf(mx, val);
    if (inst < 6)       out_fdep[((size_t)(inst * NB_ + n) * 5 + d) * HW_ + k] = val;
    else if (inst == 6) out_du[((size_t)n * 4 + d) * HW_ + k] = val;
    else                out_dl[((size_t)n * 2 + d) * HW_ + k] = val;
  }
  float ssum = 0.f;
  for (int d = 0; d < nd; ++d) { v[d] = expf(v[d] - mx); ssum += v[d]; }
  float is = 1.f / ssum;
  for (int d = 0; d < nd; ++d) {
    float sm = v[d] * is;
    if (inst < 6)       att_sm[((size_t)(inst * NB_ + n) * 5 + d) * HW_ + k] = sm;
    else if (inst == 6) da_u[((size_t)n * 4 + d) * HW_ + k] = sm;
    else                da_l[((size_t)n * 2 + d) * HW_ + k] = sm;
  }
}

// ---------------------------------------------------------------------------
// K7: dep messages + segment_sum -> xpp[v][n][10][HW]
// ---------------------------------------------------------------------------
__global__ __launch_bounds__(256) void k_msgs(
    const float* __restrict__ p_nodes, const float* __restrict__ att_sm,
    const float* __restrict__ dep_att, const float* __restrict__ rpx,
    const float* __restrict__ dp_r1, const float* __restrict__ dp_r2,
    const float* __restrict__ dp_r2b, float* __restrict__ xpp)
{
  int b = blockIdx.x;
  int tile = b % 9; b /= 9;
  int n = b % NB_;  int v = b / NB_;
  int ty0 = (tile / 3) * 16, tx0 = (tile % 3) * 16;
  __shared__ float xt[20][18][20];
  __shared__ float wl[1800];
  __shared__ float w2l[100];
  __shared__ float b2l[10];
  int t = threadIdx.x;
  for (int i = t; i < 1800; i += 256) wl[i] = dp_r1[i];
  for (int i = t; i < 100; i += 256) w2l[i] = dp_r2[i];
  if (t < 10) b2l[t] = dp_r2b[t];
  for (int i = t; i < 10 * 324; i += 256) {
    int d = i / 324; int rr = (i % 324) / 18; int cc = i % 18;
    int gy = ty0 + rr - 1, gx = tx0 + cc - 1;
    float val = 0.f;
    if (gy >= 0 && gy < 48 && gx >= 0 && gx < 48)
      val = p_nodes[((size_t)(v * NB_ + n) * 10 + d) * HW_ + gy * 48 + gx];
    xt[10 + d][rr][cc] = val;
  }
  int rr = t >> 4, cc = t & 15;
  int k = (ty0 + rr) * 48 + tx0 + cc;
  float msum[10];
  #pragma unroll
  for (int d = 0; d < 10; ++d) msum[d] = 0.f;

  for (int u = 0; u < 6; ++u) {
    if (u == v) continue;
    int ce = (v < u) ? v : v - 1;
    __syncthreads();
    const float* asrc = att_sm + ((size_t)(u * NB_ + n) * 5 + ce) * HW_;
    const float* dsrc = dep_att + (size_t)(u * NB_ + n) * HW_;
    for (int i = t; i < 10 * 324; i += 256) {
      int d = i / 324; int r2 = (i % 324) / 18; int c2 = i % 18;
      int gy = ty0 + r2 - 1, gx = tx0 + c2 - 1;
      float val = 0.f;
      if (gy >= 0 && gy < 48 && gx >= 0 && gx < 48) {
        int kk = gy * 48 + gx;
        val = asrc[kk] * dsrc[kk] * rpx[((size_t)n * 10 + d) * HW_ + kk];
      }
      xt[d][r2][c2] = val;
    }
    __syncthreads();
    float y[10];
    #pragma unroll
    for (int d = 0; d < 10; ++d) y[d] = 0.f;
    for (int ic = 0; ic < 20; ++ic)
      #pragma unroll
      for (int kh = 0; kh < 3; ++kh)
        #pragma unroll
        for (int kw = 0; kw < 3; ++kw) {
          float xv = xt[ic][rr + kh][cc + kw];
          #pragma unroll
          for (int d = 0; d < 10; ++d)
            y[d] = fmaf(wl[(d * 20 + ic) * 9 + kh * 3 + kw], xv, y[d]);
        }
    #pragma unroll
    for (int d = 0; d < 10; ++d) y[d] = fmaxf(y[d], 0.f);
    #pragma unroll
    for (int d = 0; d < 10; ++d) {
      float s = b2l[d];
      #pragma unroll
      for (int j = 0; j < 10; ++j) s = fmaf(w2l[d * 10 + j], y[j], s);
      msum[d] += sigmoidf_(s);
    }
  }
  #pragma unroll
  for (int d = 0; d < 10; ++d)
    xpp[((size_t)(v * NB_ + n) * 10 + d) * HW_ + k] = msum[d];
}

// ---------------------------------------------------------------------------
// K8: du/dl parts conv + combine with alpha*xpp + GRU  (nodes 1..6)
// ---------------------------------------------------------------------------
__global__ __launch_bounds__(256) void k_parts_gru(
    const float* __restrict__ h_nodes, const float* __restrict__ p_nodes,
    const float* __restrict__ h_att,
    const float* __restrict__ da_u, const float* __restrict__ da_l,
    const float* __restrict__ du_r1, const float* __restrict__ du_r2,
    const float* __restrict__ dl_r1, const float* __restrict__ dl_r2,
    const float* __restrict__ xpp, const float* __restrict__ alpha,
    const float* __restrict__ gru_gw, const float* __restrict__ gru_gb,
    const float* __restrict__ gru_cw, float* __restrict__ p_new)
{
  int b = blockIdx.x;
  int tile = b % 9; b /= 9;
  int n = b % NB_;  int vp = b / NB_ + 1;
  int ty0 = (tile / 3) * 16, tx0 = (tile % 3) * 16;
  bool isU = (vp <= 4);
  int j = isU ? vp - 1 : vp - 5;
  const float* parent = h_nodes + ((size_t)((isU ? 1 : 2) * NB_ + n) * 10) * HW_;
  const float* patt   = h_att + (size_t)((isU ? 1 : 2) * NB_ + n) * HW_;
  const float* da     = isU ? (da_u + ((size_t)n * 4 + j) * HW_) : (da_l + ((size_t)n * 2 + j) * HW_);
  const float* child  = p_nodes + (size_t)(vp * NB_ + n) * 10 * HW_;
  const float* r1 = isU ? du_r1 : dl_r1;
  const float* r2 = isU ? du_r2 : dl_r2;

  __shared__ float xt[20][18][20];
  __shared__ float wl[1800];
  __shared__ float w2l[100];
  int t = threadIdx.x;
  for (int i = t; i < 1800; i += 256) wl[i] = r1[i];
  for (int i = t; i < 100; i += 256) w2l[i] = r2[i];
  for (int i = t; i < 20 * 324; i += 256) {
    int d = i / 324; int rr = (i % 324) / 18; int cc = i % 18;
    int gy = ty0 + rr - 1, gx = tx0 + cc - 1;
    float val = 0.f;
    if (gy >= 0 && gy < 48 && gx >= 0 && gx < 48) {
      int kk = gy * 48 + gx;
      val = (d < 10) ? parent[(size_t)d * HW_ + kk] * da[kk] * patt[kk]
                     : child[(size_t)(d - 10) * HW_ + kk];
    }
    xt[d][rr][cc] = val;
  }
  __syncthreads();
  int rr = t >> 4, cc = t & 15;
  int k = (ty0 + rr) * 48 + tx0 + cc;
  float y[10];
  #pragma unroll
  for (int d = 0; d < 10; ++d) y[d] = 0.f;
  for (int ic = 0; ic < 20; ++ic)
    #pragma unroll
    for (int kh = 0; kh < 3; ++kh)
      #pragma unroll
      for (int kw = 0; kw < 3; ++kw) {
        float xv = xt[ic][rr + kh][cc + kw];
        #pragma unroll
        for (int d = 0; d < 10; ++d)
          y[d] = fmaf(wl[(d * 20 + ic) * 9 + kh * 3 + kw], xv, y[d]);
      }
  float yr[10];
  #pragma unroll
  for (int d = 0; d < 10; ++d) yr[d] = fmaxf(y[d], 0.f);

  float al = alpha[0];
  float x[10], h[10];
  #pragma unroll
  for (int d = 0; d < 10; ++d) {
    float s = 0.f;
    #pragma unroll
    for (int jj = 0; jj < 10; ++jj) s = fmaf(w2l[d * 10 + jj], yr[jj], s);
    float parts = fmaxf(s, 0.f);
    x[d] = parts + al * xpp[((size_t)((vp - 1) * NB_ + n) * 10 + d) * HW_ + k];
    h[d] = p_nodes[((size_t)(vp * NB_ + n) * 10 + d) * HW_ + k];
  }
  const float* gw = gru_gw + (size_t)vp * 40;
  const float* gb = gru_gb + (size_t)vp * 2;
  const float* cw = gru_cw + (size_t)vp * 200;
  float g0 = gb[0], g1 = gb[1];
  #pragma unroll
  for (int d = 0; d < 10; ++d) {
    g0 = fmaf(gw[d], x[d], fmaf(gw[10 + d], h[d], g0));
    g1 = fmaf(gw[20 + d], x[d], fmaf(gw[30 + d], h[d], g1));
  }
  float rg = sigmoidf_(g0);
  float ug = sigmoidf_(g1);
  #pragma unroll
  for (int d = 0; d < 10; ++d) {
    float s = 0.f;
    const float* cr = cw + d * 20;
    #pragma unroll
    for (int jj = 0; jj < 10; ++jj)
      s = fmaf(cr[jj], x[jj], fmaf(cr[10 + jj], rg * h[jj], s));
    float cn = fmaxf(s, 0.f);
    p_new[((size_t)(vp * NB_ + n) * 10 + d) * HW_ + k] = (1.f - ug) * h[d] + ug * cn;
  }
}

// ---------------------------------------------------------------------------
// K9: GRU for node 0
// ---------------------------------------------------------------------------
__global__ __launch_bounds__(256) void k_gru0(
    const float* __restrict__ h_nodes, const float* __restrict__ p_nodes,
    const float* __restrict__ gru_gw, const float* __restrict__ gru_gb,
    const float* __restrict__ gru_cw, float* __restrict__ p_new)
{
  int idx = blockIdx.x * 256 + threadIdx.x;
  if (idx >= NB_ * HW_) return;
  int n = idx / HW_, k = idx - n * HW_;
  float x[10], h[10];
  #pragma unroll
  for (int d = 0; d < 10; ++d) {
    x[d] = h_nodes[((size_t)n * 10 + d) * HW_ + k];
    h[d] = p_nodes[((size_t)n * 10 + d) * HW_ + k];
  }
  float g0 = gru_gb[0], g1 = gru_gb[1];
  #pragma unroll
  for (int d = 0; d < 10; ++d) {
    g0 = fmaf(gru_gw[d], x[d], fmaf(gru_gw[10 + d], h[d], g0));
    g1 = fmaf(gru_gw[20 + d], x[d], fmaf(gru_gw[30 + d], h[d], g1));
  }
  float rg = sigmoidf_(g0);
  float ug = sigmoidf_(g1);
  #pragma unroll
  for (int d = 0; d < 10; ++d) {
    float s = 0.f;
    const float* cr = gru_cw + d * 20;
    #pragma unroll
    for (int jj = 0; jj < 10; ++jj)
      s = fmaf(cr[jj], x[jj], fmaf(cr[10 + jj], rg * h[jj], s));
    float cn = fmaxf(s, 0.f);
    p_new[((size_t)n * 10 + d) * HW_ + k] = (1.f - ug) * h[d] + ug * cn;
  }
}

// ---------------------------------------------------------------------------
extern "C" void kernel_launch(void* const* d_in, const int* in_sizes, int n_in,
                              void* d_out, int out_size, void* d_ws, size_t ws_size,
                              hipStream_t stream) {
  (void)in_sizes; (void)n_in; (void)out_size; (void)ws_size;
  const float* h_nodes = (const float*)d_in[1];
  const float* p_nodes = (const float*)d_in[2];
  const float* xp      = (const float*)d_in[3];
  const float* h_att   = (const float*)d_in[4];
  const float* p_att   = (const float*)d_in[5];
  const float* dc_q_w  = (const float*)d_in[6];
  const float* dc_q_b  = (const float*)d_in[7];
  const float* dc_k_w  = (const float*)d_in[8];
  const float* dc_k_b  = (const float*)d_in[9];
  const float* dc_p_w  = (const float*)d_in[10];
  const float* dc_p_b  = (const float*)d_in[11];
  const float* ctx_w1  = (const float*)d_in[12];
  const float* ctx_w2  = (const float*)d_in[13];
  const float* ctx_b2  = (const float*)d_in[14];
  const float* du_a1   = (const float*)d_in[15];
  const float* du_a2   = (const float*)d_in[16];
  const float* du_a2b  = (const float*)d_in[17];
  const float* du_r1   = (const float*)d_in[18];
  const float* du_r2   = (const float*)d_in[19];
  const float* dl_a1   = (const float*)d_in[20];
  const float* dl_a2   = (const float*)d_in[21];
  const float* dl_a2b  = (const float*)d_in[22];
  const float* dl_r1   = (const float*)d_in[23];
  const float* dl_r2   = (const float*)d_in[24];
  const float* dp_proj = (const float*)d_in[25];
  const float* dp_r1   = (const float*)d_in[26];
  const float* dp_r2   = (const float*)d_in[27];
  const float* dp_r2b  = (const float*)d_in[28];
  const float* gru_gw  = (const float*)d_in[29];
  const float* gru_gb  = (const float*)d_in[30];
  const float* gru_cw  = (const float*)d_in[31];
  const float* alpha   = (const float*)d_in[32];

  float* ws = (float*)d_ws;
  float* keydot  = ws;                 // 4608
  float* qdot    = ws + 4608;          // 16
  float* dep_att = ws + 4624;          // 27648
  float* rpx     = ws + 32272;         // 46080
  float* att_sm  = ws + 78352;         // 138240
  float* da_u    = ws + 216592;        // 18432
  float* da_l    = ws + 235024;        // 9216
  float* xpp     = ws + 244240;        // 276480
  float* w0      = ws + 520720;        // 18432 -> floats end at 539152
  // na_ws / hu_ws alias att_sm region (dead until k_heads writes it)
  float* na_ws   = att_sm;             // 12*2304 = 27648
  float* hu_ws   = att_sm + 27648;     // 12*256  = 3072
  unsigned short* us = (unsigned short*)(ws + 539152);
  unsigned short* xbf = us;                       // 1,179,648
  unsigned short* wt  = us + 1179648;             // 4,718,592
  unsigned short* h1  = us + 5898240;             // 9,437,184

  float* out      = (float*)d_out;
  float* out_pnew = out;               // 322560
  float* out_du   = out + 322560;      // 18432
  float* out_dl   = out + 340992;      // 9216
  float* out_fdep = out + 350208;      // 138240

  k_xbf<<<72, 256, 0, stream>>>(xp, xbf);
  k_wbf<<<2048, 256, 0, stream>>>(ctx_w1, du_a1, dl_a1, wt, w0);
  k_sm<<<12, 256, 0, stream>>>(p_att, na_ws);
  k_huc<<<192, 256, 0, stream>>>(xp, na_ws, hu_ws);
  k_qdot<<<12, 256, 0, stream>>>(na_ws, hu_ws, dc_q_w, dc_q_b, dc_p_w, qdot);
  k_keydot<<<288, 256, 0, stream>>>(xbf, dc_k_w, dc_k_b, dc_p_w, keydot);
  k_depatt<<<108, 256, 0, stream>>>(p_att, keydot, qdot, dc_p_b, dep_att);
  k_rpx<<<18, 256, 0, stream>>>(xp, dp_proj, rpx);
  k_convmma<<<1152, 256, 0, stream>>>(xbf, wt, w0, dep_att, h_att, h1);
  k_heads<<<144, 256, 0, stream>>>(h1, ctx_w2, du_a2, dl_a2, ctx_b2, du_a2b, dl_a2b,
                                   out_fdep, out_du, out_dl, att_sm, da_u, da_l);
  k_msgs<<<108, 256, 0, stream>>>(p_nodes, att_sm, dep_att, rpx,
                                  dp_r1, dp_r2, dp_r2b, xpp);
  k_parts_gru<<<108, 256, 0, stream>>>(h_nodes, p_nodes, h_att, da_u, da_l,
                                       du_r1, du_r2, dl_r1, dl_r2, xpp, alpha,
                                       gru_gw, gru_gb, gru_cw, out_pnew);
  k_gru0<<<18, 256, 0, stream>>>(h_nodes, p_nodes, gru_gw, gru_gb, gru_cw, out_pnew);
}

// Round 4
// 380.394 us; speedup vs baseline: 6.4582x; 1.2246x over previous
//
#include <hip/hip_runtime.h>
#include <math.h>

// Problem constants: N=2, C=256, H=W=48, HID=10, P=7
constexpr int NB_ = 2;
constexpr int C_  = 256;
constexpr int HW_ = 2304;   // 48*48

typedef float f32x4 __attribute__((ext_vector_type(4)));
typedef short short8 __attribute__((ext_vector_type(8)));

__device__ __forceinline__ float coordval(int c, int k) {
  int y = k / 48, x = k - y * 48;
  switch (c) {
    case 0: return x * (1.f/24.f) - 1.f;
    case 1: return y * (1.f/24.f) - 1.f;
    case 2: return (x + 1) * (1.f/24.f) - 1.f;
    case 3: return (y + 1) * (1.f/24.f) - 1.f;
    case 4: return (x + 0.5f) * (1.f/24.f) - 1.f;
    case 5: return (y + 0.5f) * (1.f/24.f) - 1.f;
    default: return 1.f/48.f;
  }
}

__device__ __forceinline__ float sigmoidf_(float x) { return 1.f / (1.f + expf(-x)); }
__device__ __forceinline__ unsigned short f2bf(float f) {
  unsigned int u = __float_as_uint(f);
  unsigned int r = (u + 0x7FFFu + ((u >> 16) & 1u)) >> 16;
  return (unsigned short)r;
}
__device__ __forceinline__ float bf2f(unsigned short h) {
  return __uint_as_float(((unsigned int)h) << 16);
}

// ---------------------------------------------------------------------------
// P1: xbf[n][y][x][c] = bf16(xp[n][c][y*48+x])   (NHWC bf16)
// ---------------------------------------------------------------------------
__global__ __launch_bounds__(256) void k_xbf(
    const float* __restrict__ xp, unsigned short* __restrict__ xbf)
{
  __shared__ float xt[64][65];
  int t = threadIdx.x;
  int px0 = blockIdx.x * 64;
  int n = px0 / HW_, k0 = px0 - n * HW_;
  for (int cb = 0; cb < 4; ++cb) {
    __syncthreads();
    for (int i = t; i < 4096; i += 256) {
      int cl = i >> 6, pxl = i & 63;
      xt[cl][pxl] = xp[((size_t)(n * C_ + cb * 64 + cl)) * HW_ + k0 + pxl];
    }
    __syncthreads();
    for (int i = t; i < 4096; i += 256) {
      int pxl = i >> 6, cl = i & 63;
      xbf[((size_t)(n * HW_ + k0 + pxl)) * 256 + cb * 64 + cl] = f2bf(xt[cl][pxl]);
    }
  }
}

// ---------------------------------------------------------------------------
// P2: weight transform to MFMA fragment order.
// wt frag addr: (((inst*9+pos)*8 + chunk)*16 + mf)*512 + lane*8 + j
//   where oc = mf*16 + (lane&15), c = chunk*32 + (lane>>4)*8 + j
// ---------------------------------------------------------------------------
__global__ __launch_bounds__(256) void k_wbf(
    const float* __restrict__ ctx_w1, const float* __restrict__ du_a1,
    const float* __restrict__ dl_a1,
    unsigned short* __restrict__ wt, float* __restrict__ w0)
{
  int inst = blockIdx.x >> 8, oc = blockIdx.x & 255;
  const float* src = (inst < 6) ? (ctx_w1 + (size_t)inst * 256 * 2313)
                   : (inst == 6 ? du_a1 : dl_a1);
  src += (size_t)oc * 2313;
  int mf = oc >> 4, lr = oc & 15;
  int t = threadIdx.x;
  for (int i = t; i < 2304; i += 256) {
    int pos = i >> 8, c = i & 255;
    float v = src[(size_t)(c + 1) * 9 + pos];
    int chunk = c >> 5, lg = (c >> 3) & 3, j = c & 7;
    size_t addr = ((((size_t)(inst * 9 + pos) * 8 + chunk) * 16 + mf) << 9)
                  + (size_t)(lg * 16 + lr) * 8 + j;
    wt[addr] = f2bf(v);
  }
  if (t < 9) w0[((size_t)inst * 256 + oc) * 9 + t] = src[t];
}

// ---------------------------------------------------------------------------
// K1: keydot via MFMA. M=64 (d), N=256 px/block (18 blocks), K=264 pad 288.
// ---------------------------------------------------------------------------
__global__ __launch_bounds__(256) void k_keymma(
    const unsigned short* __restrict__ xbf, const float* __restrict__ dc_k_w,
    const float* __restrict__ dc_k_b, const float* __restrict__ dc_p_w,
    float* __restrict__ keydot)
{
  __shared__ unsigned short wlf[64 * 296];  // [d][c pad296] bf16
  __shared__ unsigned short xl[256 * 40];   // [pxl][32ch pad40] per chunk
  int t = threadIdx.x;
  for (int i = t; i < 64 * 264; i += 256) {
    int d = i / 264, c = i - d * 264;
    wlf[d * 296 + c] = f2bf(dc_k_w[i]);
  }
  for (int i = t; i < 64 * 32; i += 256) {
    int d = i >> 5, c = 264 + (i & 31);
    wlf[d * 296 + c] = 0;
  }
  int px0 = blockIdx.x * 256;
  int w = t >> 6, l = t & 63;
  int lr = l & 15, lg = l >> 4;

  f32x4 acc[4][4];
  #pragma unroll
  for (int mi = 0; mi < 4; ++mi)
    #pragma unroll
    for (int nf = 0; nf < 4; ++nf) acc[mi][nf] = (f32x4){0.f,0.f,0.f,0.f};

  for (int ch = 0; ch < 9; ++ch) {
    __syncthreads();
    for (int i = t; i < 1024; i += 256) {
      int pxl = i >> 2, q = i & 3;
      int px = px0 + pxl, n = px / HW_, k = px - n * HW_;
      int c0 = ch * 32 + q * 8;
      short8 v;
      if (c0 + 7 < 256) {
        v = *(const short8*)(xbf + ((size_t)(n * HW_ + k)) * 256 + c0);
      } else {
        #pragma unroll
        for (int j = 0; j < 8; ++j) {
          int cc = c0 + j;
          float f = (cc < 256) ? bf2f(xbf[((size_t)(n * HW_ + k)) * 256 + cc])
                   : (cc < 264 ? coordval(cc - 256, k) : 0.f);
          v[j] = (short)f2bf(f);
        }
      }
      *(short8*)(xl + pxl * 40 + q * 8) = v;
    }
    __syncthreads();
    short8 bfr[4];
    #pragma unroll
    for (int nf = 0; nf < 4; ++nf)
      bfr[nf] = *(const short8*)(xl + (w * 64 + nf * 16 + lr) * 40 + lg * 8);
    #pragma unroll
    for (int mi = 0; mi < 4; ++mi) {
      short8 a = *(const short8*)(wlf + (mi * 16 + lr) * 296 + ch * 32 + lg * 8);
      #pragma unroll
      for (int nf = 0; nf < 4; ++nf)
        acc[mi][nf] = __builtin_amdgcn_mfma_f32_16x16x32_bf16(a, bfr[nf], acc[mi][nf], 0, 0, 0);
    }
  }

  #pragma unroll
  for (int nf = 0; nf < 4; ++nf) {
    float s = 0.f;
    #pragma unroll
    for (int mi = 0; mi < 4; ++mi)
      #pragma unroll
      for (int r = 0; r < 4; ++r) {
        int d = mi * 16 + lg * 4 + r;
        s += dc_p_w[64 + d] * fmaxf(acc[mi][nf][r] + dc_k_b[d], 0.f);
      }
    s += __shfl_down(s, 32, 64);
    s += __shfl_down(s, 16, 64);
    if (lg == 0) keydot[px0 + w * 64 + nf * 16 + lr] = s;
  }
}

// ---------------------------------------------------------------------------
// K2a: na[pair][k] = softmax over HW of p_att[1+i][n]
// ---------------------------------------------------------------------------
__global__ __launch_bounds__(256) void k_sm(
    const float* __restrict__ p_att, float* __restrict__ na_ws)
{
  __shared__ float red[16];
  int t = threadIdx.x;
  const float* att = p_att + (size_t)(NB_ + blockIdx.x) * HW_;
  float* na = na_ws + (size_t)blockIdx.x * HW_;

  float m = -1e30f;
  for (int k = t; k < HW_; k += 256) m = fmaxf(m, att[k]);
  #pragma unroll
  for (int off = 32; off > 0; off >>= 1) m = fmaxf(m, __shfl_down(m, off, 64));
  if ((t & 63) == 0) red[t >> 6] = m;
  __syncthreads();
  if (t == 0) { float mm = red[0]; for (int w = 1; w < 4; ++w) mm = fmaxf(mm, red[w]); red[0] = mm; }
  __syncthreads();
  m = red[0];
  float s = 0.f;
  for (int k = t; k < HW_; k += 256) s += expf(att[k] - m);
  #pragma unroll
  for (int off = 32; off > 0; off >>= 1) s += __shfl_down(s, off, 64);
  if ((t & 63) == 0) red[8 + (t >> 6)] = s;
  __syncthreads();
  if (t == 0) { float ss = 0; for (int w = 0; w < 4; ++w) ss += red[8 + w]; red[8] = ss; }
  __syncthreads();
  float inv = 1.f / red[8];
  for (int k = t; k < HW_; k += 256) na[k] = expf(att[k] - m) * inv;
}

// ---------------------------------------------------------------------------
// K2b: hu[pair][c] = sum_k xp[n,c,k] * na[pair][k]
// ---------------------------------------------------------------------------
__global__ __launch_bounds__(256) void k_huc(
    const float* __restrict__ xp, const float* __restrict__ na_ws,
    float* __restrict__ hu_ws)
{
  __shared__ float na[HW_];
  int b = blockIdx.x;
  int cb = b & 15; int pair = b >> 4;
  int n = pair % NB_;
  int t = threadIdx.x;
  const float* nag = na_ws + (size_t)pair * HW_;
  for (int k = t; k < HW_; k += 256) na[k] = nag[k];
  __syncthreads();
  int wv = t >> 6, l = t & 63;
  #pragma unroll
  for (int cq = 0; cq < 4; ++cq) {
    int c = cb * 16 + wv * 4 + cq;
    const float* x = xp + (size_t)(n * C_ + c) * HW_;
    float a = 0.f;
    for (int k = l; k < HW_; k += 64) a = fmaf(x[k], na[k], a);
    #pragma unroll
    for (int off = 32; off > 0; off >>= 1) a += __shfl_down(a, off, 64);
    if (l == 0) hu_ws[(size_t)pair * 256 + c] = a;
  }
}

// ---------------------------------------------------------------------------
// K2c: co coords + q + qdot per pair
// ---------------------------------------------------------------------------
__global__ __launch_bounds__(256) void k_qdot(
    const float* __restrict__ na_ws, const float* __restrict__ hu_ws,
    const float* __restrict__ dc_q_w, const float* __restrict__ dc_q_b,
    const float* __restrict__ dc_p_w, float* __restrict__ qdot)
{
  __shared__ float na[HW_];
  __shared__ float co[8];
  __shared__ float hu[256];
  __shared__ float ql[64];
  int t = threadIdx.x;
  int pair = blockIdx.x;
  const float* nag = na_ws + (size_t)pair * HW_;
  for (int k = t; k < HW_; k += 256) na[k] = nag[k];
  hu[t] = hu_ws[(size_t)pair * 256 + t];
  __syncthreads();
  int wv = t >> 6, l = t & 63;
  #pragma unroll
  for (int q = 0; q < 2; ++q) {
    int cc = wv * 2 + q;
    float a = 0.f;
    for (int k = l; k < HW_; k += 64) a = fmaf(coordval(cc, k), na[k], a);
    #pragma unroll
    for (int off = 32; off > 0; off >>= 1) a += __shfl_down(a, off, 64);
    if (l == 0) co[cc] = a;
  }
  __syncthreads();
  if (t < 64) {
    float a = dc_q_b[t];
    const float* wr = dc_q_w + (size_t)t * 264;
    for (int c = 0; c < 256; ++c) a = fmaf(wr[c], hu[c], a);
    #pragma unroll
    for (int c = 0; c < 8; ++c) a = fmaf(wr[256 + c], co[c], a);
    ql[t] = fmaxf(a, 0.f) * dc_p_w[t];
  }
  __syncthreads();
  if (t == 0) {
    float a = 0.f;
    for (int d = 0; d < 64; ++d) a += ql[d];
    qdot[pair] = a;
  }
}

// ---------------------------------------------------------------------------
// K3: dep_att
// ---------------------------------------------------------------------------
__global__ __launch_bounds__(256) void k_depatt(
    const float* __restrict__ p_att, const float* __restrict__ keydot,
    const float* __restrict__ qdot, const float* __restrict__ dc_p_b,
    float* __restrict__ dep_att)
{
  int idx = blockIdx.x * 256 + threadIdx.x;
  if (idx >= 6 * NB_ * HW_) return;
  int e = idx / (NB_ * HW_); int r = idx - e * NB_ * HW_;
  int n = r / HW_, k = r - n * HW_;
  float energy = qdot[e * NB_ + n] + keydot[n * HW_ + k] + dc_p_b[0];
  float a = sigmoidf_(energy);
  float hu = p_att[(size_t)((1 + e) * NB_ + n) * HW_ + k];
  dep_att[idx] = a * (1.f - hu);
}

// ---------------------------------------------------------------------------
// K4: rpx
// ---------------------------------------------------------------------------
__global__ __launch_bounds__(256) void k_rpx(
    const float* __restrict__ xp, const float* __restrict__ dp_proj,
    float* __restrict__ rpx)
{
  __shared__ float pj[10 * 256];
  int t = threadIdx.x;
  for (int i = t; i < 2560; i += 256) pj[i] = dp_proj[i];
  __syncthreads();
  int p = blockIdx.x * 256 + t;
  if (p >= NB_ * HW_) return;
  int n = p / HW_, k = p - n * HW_;
  float acc[10];
  #pragma unroll
  for (int d = 0; d < 10; ++d) acc[d] = 0.f;
  const float* x = xp + (size_t)n * C_ * HW_ + k;
  for (int c = 0; c < 256; ++c) {
    float v = x[(size_t)c * HW_];
    #pragma unroll
    for (int d = 0; d < 10; ++d) acc[d] = fmaf(pj[d * 256 + c], v, acc[d]);
  }
  #pragma unroll
  for (int d = 0; d < 10; ++d) rpx[(size_t)(n * 10 + d) * HW_ + k] = fmaxf(acc[d], 0.f);
}

// ---------------------------------------------------------------------------
// K5: MFMA implicit-GEMM conv. Block = 128 oc x 128 px, 4 waves.
// Wave = 64 oc (4 m-frags) x 64 px (4 n-frags). Coalesced frag-order A loads.
// ---------------------------------------------------------------------------
__global__ __launch_bounds__(256) void k_convmma(
    const unsigned short* __restrict__ xbf, const unsigned short* __restrict__ wt,
    const float* __restrict__ w0, const float* __restrict__ dep_att,
    const float* __restrict__ h_att, unsigned short* __restrict__ h1)
{
  int b = blockIdx.x;
  int pxt = b % 18; b /= 18;
  int ocb = b % 2;  b /= 2;
  int n = b % NB_;  int inst = b / NB_;
  int y0 = (pxt / 6) * 16, x0 = (pxt % 6) * 8;

  __shared__ unsigned short xs[180 * 40];
  __shared__ float asf[180];
  __shared__ float w0l[128 * 9];

  const float* asrc = (inst < 6) ? dep_att + (size_t)(inst * NB_ + n) * HW_
                    : h_att + (size_t)(((inst == 6) ? 1 : 2) * NB_ + n) * HW_;

  int t = threadIdx.x;
  for (int i = t; i < 180; i += 256) {
    int yy = i / 10, xx = i - yy * 10;
    int gy = y0 + yy - 1, gx = x0 + xx - 1;
    asf[i] = (gy >= 0 && gy < 48 && gx >= 0 && gx < 48) ? asrc[gy * 48 + gx] : 0.f;
  }
  for (int i = t; i < 1152; i += 256) {
    int oc = i / 9, pos = i - oc * 9;
    w0l[i] = w0[((size_t)inst * 256 + ocb * 128 + oc) * 9 + pos];
  }

  int w = t >> 6, l = t & 63;
  int wm = w >> 1, wn = w & 1;
  int lr = l & 15, lg = l >> 4;

  f32x4 acc[4][4];
  #pragma unroll
  for (int mi = 0; mi < 4; ++mi)
    #pragma unroll
    for (int nf = 0; nf < 4; ++nf) acc[mi][nf] = (f32x4){0.f,0.f,0.f,0.f};

  const unsigned short* xg = xbf + (size_t)n * HW_ * 256;
  int mf0 = ocb * 8 + wm * 4;

  for (int chunk = 0; chunk < 8; ++chunk) {
    __syncthreads();
    for (int i = t; i < 720; i += 256) {
      int pos = i >> 2, q = i & 3;
      int yy = pos / 10, xx = pos - yy * 10;
      int gy = y0 + yy - 1, gx = x0 + xx - 1;
      short8 v = (short8){0,0,0,0,0,0,0,0};
      if (gy >= 0 && gy < 48 && gx >= 0 && gx < 48)
        v = *(const short8*)(xg + ((size_t)(gy * 48 + gx)) * 256 + chunk * 32 + q * 8);
      *(short8*)(xs + pos * 40 + q * 8) = v;
    }
    __syncthreads();

    #pragma unroll
    for (int pos = 0; pos < 9; ++pos) {
      short8 av[4];
      #pragma unroll
      for (int mi = 0; mi < 4; ++mi)
        av[mi] = *(const short8*)(wt +
            ((((size_t)(inst * 9 + pos) * 8 + chunk) * 16 + mf0 + mi) << 9) + l * 8);
      int kh = pos / 3, kw = pos - kh * 3;
      short8 bfr[4];
      #pragma unroll
      for (int nf = 0; nf < 4; ++nf) {
        int p = wn * 64 + nf * 16 + lr;
        int y = p >> 3, x = p & 7;
        bfr[nf] = *(const short8*)(xs + ((y + kh) * 10 + (x + kw)) * 40 + lg * 8);
      }
      #pragma unroll
      for (int mi = 0; mi < 4; ++mi)
        #pragma unroll
        for (int nf = 0; nf < 4; ++nf)
          acc[mi][nf] = __builtin_amdgcn_mfma_f32_16x16x32_bf16(av[mi], bfr[nf], acc[mi][nf], 0, 0, 0);
    }
  }

  size_t h1base = ((size_t)(inst * NB_ + n) * 256) * HW_;
  #pragma unroll
  for (int mi = 0; mi < 4; ++mi) {
    #pragma unroll
    for (int nf = 0; nf < 4; ++nf) {
      int p = wn * 64 + nf * 16 + lr;
      int y = p >> 3, x = p & 7;
      #pragma unroll
      for (int r = 0; r < 4; ++r) {
        int ocl = (wm * 4 + mi) * 16 + lg * 4 + r;   // 0..127
        float v = acc[mi][nf][r];
        const float* wr = &w0l[ocl * 9];
        #pragma unroll
        for (int pos = 0; pos < 9; ++pos) {
          int kh = pos / 3, kw = pos - kh * 3;
          v = fmaf(wr[pos], asf[(y + kh) * 10 + (x + kw)], v);
        }
        v = fmaxf(v, 0.f);
        int gk = (y0 + y) * 48 + x0 + x;
        h1[h1base + (size_t)(ocb * 128 + ocl) * HW_ + gk] = f2bf(v);
      }
    }
  }
}

// ---------------------------------------------------------------------------
// K6: heads
// ---------------------------------------------------------------------------
__global__ __launch_bounds__(256) void k_heads(
    const unsigned short* __restrict__ h1,
    const float* __restrict__ ctx_w2, const float* __restrict__ du_a2,
    const float* __restrict__ dl_a2,
    const float* __restrict__ ctx_b2, const float* __restrict__ du_a2b,
    const float* __restrict__ dl_a2b,
    float* __restrict__ out_fdep, float* __restrict__ out_du, float* __restrict__ out_dl,
    float* __restrict__ att_sm, float* __restrict__ da_u, float* __restrict__ da_l)
{
  __shared__ float w2l[5 * 256];
  int bid = blockIdx.x;
  int pc = bid % 9; bid /= 9;
  int n = bid % NB_; int inst = bid / NB_;
  int nd = (inst < 6) ? 5 : (inst == 6 ? 4 : 2);
  const float* w2 = (inst < 6) ? ctx_w2 + (size_t)inst * 5 * 256
                               : (inst == 6 ? du_a2 : dl_a2);
  int t = threadIdx.x;
  for (int i = t; i < 1280; i += 256) w2l[i] = (i < nd * 256) ? w2[i] : 0.f;
  __syncthreads();
  int k = pc * 256 + t;
  const unsigned short* hb = h1 + ((size_t)(inst * NB_ + n) * 256) * HW_ + k;
  float s[5] = {0.f, 0.f, 0.f, 0.f, 0.f};
  for (int oc = 0; oc < 256; ++oc) {
    float hv = bf2f(hb[(size_t)oc * HW_]);
    #pragma unroll
    for (int d = 0; d < 5; ++d) s[d] = fmaf(w2l[d * 256 + oc], hv, s[d]);
  }
  float v[5];
  float mx = -1e30f;
  for (int d = 0; d < nd; ++d) {
    float bsum = (inst < 6) ? ctx_b2[inst * 5 + d] : (inst == 6 ? du_a2b[d] : dl_a2b[d]);
    float val = s[d] + bsum;
    v[d] = val;
    mx = fmaxf(mx, val);
    if (inst < 6)       out_fdep[((size_t)(inst * NB_ + n) * 5 + d) * HW_ + k] = val;
    else if (inst == 6) out_du[((size_t)n * 4 + d) * HW_ + k] = val;
    else                out_dl[((size_t)n * 2 + d) * HW_ + k] = val;
  }
  float ssum = 0.f;
  for (int d = 0; d < nd; ++d) { v[d] = expf(v[d] - mx); ssum += v[d]; }
  float is = 1.f / ssum;
  for (int d = 0; d < nd; ++d) {
    float sm = v[d] * is;
    if (inst < 6)       att_sm[((size_t)(inst * NB_ + n) * 5 + d) * HW_ + k] = sm;
    else if (inst == 6) da_u[((size_t)n * 4 + d) * HW_ + k] = sm;
    else                da_l[((size_t)n * 2 + d) * HW_ + k] = sm;
  }
}

// ---------------------------------------------------------------------------
// K7a: yhv[v][n][d][k] = hv-half of the dep_msg conv (shared by 5 edges)
// ---------------------------------------------------------------------------
__global__ __launch_bounds__(256) void k_yhv(
    const float* __restrict__ p_nodes, const float* __restrict__ dp_r1,
    float* __restrict__ yhv_ws)
{
  int b = blockIdx.x;
  int tile = b % 9; b /= 9;
  int n = b % NB_;  int v = b / NB_;
  int ty0 = (tile / 3) * 16, tx0 = (tile % 3) * 16;
  __shared__ float xt[10][18][20];
  __shared__ float wl[900];
  int t = threadIdx.x;
  for (int i = t; i < 900; i += 256) {
    int d = i / 90; int rest = i - d * 90; int ic = rest / 9; int pos = rest - ic * 9;
    wl[i] = dp_r1[(d * 20 + 10 + ic) * 9 + pos];
  }
  for (int i = t; i < 10 * 324; i += 256) {
    int d = i / 324; int rr = (i % 324) / 18; int cc = i % 18;
    int gy = ty0 + rr - 1, gx = tx0 + cc - 1;
    float val = 0.f;
    if (gy >= 0 && gy < 48 && gx >= 0 && gx < 48)
      val = p_nodes[((size_t)(v * NB_ + n) * 10 + d) * HW_ + gy * 48 + gx];
    xt[d][rr][cc] = val;
  }
  __syncthreads();
  int rr = t >> 4, cc = t & 15;
  int k = (ty0 + rr) * 48 + tx0 + cc;
  float y[10];
  #pragma unroll
  for (int d = 0; d < 10; ++d) y[d] = 0.f;
  for (int ic = 0; ic < 10; ++ic)
    #pragma unroll
    for (int kh = 0; kh < 3; ++kh)
      #pragma unroll
      for (int kw = 0; kw < 3; ++kw) {
        float xv = xt[ic][rr + kh][cc + kw];
        #pragma unroll
        for (int d = 0; d < 10; ++d)
          y[d] = fmaf(wl[(d * 10 + ic) * 9 + kh * 3 + kw], xv, y[d]);
      }
  #pragma unroll
  for (int d = 0; d < 10; ++d)
    yhv_ws[((size_t)(v * NB_ + n) * 10 + d) * HW_ + k] = y[d];
}

// ---------------------------------------------------------------------------
// K7b: one edge per block: m-half conv + combine + r2 + sigmoid -> msg_ws
// grid = v(6) x ui(5) x n(2) x tile(9) = 540
// ---------------------------------------------------------------------------
__global__ __launch_bounds__(256) void k_msgs_edge(
    const float* __restrict__ att_sm, const float* __restrict__ dep_att,
    const float* __restrict__ rpx, const float* __restrict__ yhv_ws,
    const float* __restrict__ dp_r1, const float* __restrict__ dp_r2,
    const float* __restrict__ dp_r2b, float* __restrict__ msg_ws)
{
  int b = blockIdx.x;
  int tile = b % 9; b /= 9;
  int n = b % NB_;  b /= NB_;
  int ui = b % 5;   int v = b / 5;
  int u = (ui < v) ? ui : ui + 1;
  int ce = (v < u) ? v : v - 1;
  int ty0 = (tile / 3) * 16, tx0 = (tile % 3) * 16;

  __shared__ float xt[10][18][20];
  __shared__ float wl[900];
  __shared__ float w2l[100];
  __shared__ float b2l[10];
  int t = threadIdx.x;
  for (int i = t; i < 900; i += 256) {
    int d = i / 90; int rest = i - d * 90; int ic = rest / 9; int pos = rest - ic * 9;
    wl[i] = dp_r1[(d * 20 + ic) * 9 + pos];
  }
  for (int i = t; i < 100; i += 256) w2l[i] = dp_r2[i];
  if (t < 10) b2l[t] = dp_r2b[t];

  const float* asrc = att_sm + ((size_t)(u * NB_ + n) * 5 + ce) * HW_;
  const float* dsrc = dep_att + (size_t)(u * NB_ + n) * HW_;
  for (int i = t; i < 10 * 324; i += 256) {
    int d = i / 324; int rr = (i % 324) / 18; int cc = i % 18;
    int gy = ty0 + rr - 1, gx = tx0 + cc - 1;
    float val = 0.f;
    if (gy >= 0 && gy < 48 && gx >= 0 && gx < 48) {
      int kk = gy * 48 + gx;
      val = asrc[kk] * dsrc[kk] * rpx[((size_t)n * 10 + d) * HW_ + kk];
    }
    xt[d][rr][cc] = val;
  }
  __syncthreads();
  int rr = t >> 4, cc = t & 15;
  int k = (ty0 + rr) * 48 + tx0 + cc;
  float y[10];
  #pragma unroll
  for (int d = 0; d < 10; ++d) y[d] = 0.f;
  for (int ic = 0; ic < 10; ++ic)
    #pragma unroll
    for (int kh = 0; kh < 3; ++kh)
      #pragma unroll
      for (int kw = 0; kw < 3; ++kw) {
        float xv = xt[ic][rr + kh][cc + kw];
        #pragma unroll
        for (int d = 0; d < 10; ++d)
          y[d] = fmaf(wl[(d * 10 + ic) * 9 + kh * 3 + kw], xv, y[d]);
      }
  float s[10];
  #pragma unroll
  for (int d = 0; d < 10; ++d)
    s[d] = fmaxf(y[d] + yhv_ws[((size_t)(v * NB_ + n) * 10 + d) * HW_ + k], 0.f);
  #pragma unroll
  for (int d = 0; d < 10; ++d) {
    float m = b2l[d];
    #pragma unroll
    for (int j = 0; j < 10; ++j) m = fmaf(w2l[d * 10 + j], s[j], m);
    msg_ws[(((size_t)(v * 5 + ui) * NB_ + n) * 10 + d) * HW_ + k] = sigmoidf_(m);
  }
}

// ---------------------------------------------------------------------------
// K8: parts conv + alpha*sum(msgs) + GRU  (nodes 1..6)
// ---------------------------------------------------------------------------
__global__ __launch_bounds__(256) void k_parts_gru(
    const float* __restrict__ h_nodes, const float* __restrict__ p_nodes,
    const float* __restrict__ h_att,
    const float* __restrict__ da_u, const float* __restrict__ da_l,
    const float* __restrict__ du_r1, const float* __restrict__ du_r2,
    const float* __restrict__ dl_r1, const float* __restrict__ dl_r2,
    const float* __restrict__ msg_ws, const float* __restrict__ alpha,
    const float* __restrict__ gru_gw, const float* __restrict__ gru_gb,
    const float* __restrict__ gru_cw, float* __restrict__ p_new)
{
  int b = blockIdx.x;
  int tile = b % 9; b /= 9;
  int n = b % NB_;  int vp = b / NB_ + 1;
  int ty0 = (tile / 3) * 16, tx0 = (tile % 3) * 16;
  bool isU = (vp <= 4);
  int j = isU ? vp - 1 : vp - 5;
  const float* parent = h_nodes + ((size_t)((isU ? 1 : 2) * NB_ + n) * 10) * HW_;
  const float* patt   = h_att + (size_t)((isU ? 1 : 2) * NB_ + n) * HW_;
  const float* da     = isU ? (da_u + ((size_t)n * 4 + j) * HW_) : (da_l + ((size_t)n * 2 + j) * HW_);
  const float* child  = p_nodes + (size_t)(vp * NB_ + n) * 10 * HW_;
  const float* r1 = isU ? du_r1 : dl_r1;
  const float* r2 = isU ? du_r2 : dl_r2;

  __shared__ float xt[20][18][20];
  __shared__ float wl[1800];
  __shared__ float w2l[100];
  int t = threadIdx.x;
  for (int i = t; i < 1800; i += 256) wl[i] = r1[i];
  for (int i = t; i < 100; i += 256) w2l[i] = r2[i];
  for (int i = t; i < 20 * 324; i += 256) {
    int d = i / 324; int rr = (i % 324) / 18; int cc = i % 18;
    int gy = ty0 + rr - 1, gx = tx0 + cc - 1;
    float val = 0.f;
    if (gy >= 0 && gy < 48 && gx >= 0 && gx < 48) {
      int kk = gy * 48 + gx;
      val = (d < 10) ? parent[(size_t)d * HW_ + kk] * da[kk] * patt[kk]
                     : child[(size_t)(d - 10) * HW_ + kk];
    }
    xt[d][rr][cc] = val;
  }
  __syncthreads();
  int rr = t >> 4, cc = t & 15;
  int k = (ty0 + rr) * 48 + tx0 + cc;
  float y[10];
  #pragma unroll
  for (int d = 0; d < 10; ++d) y[d] = 0.f;
  for (int ic = 0; ic < 20; ++ic)
    #pragma unroll
    for (int kh = 0; kh < 3; ++kh)
      #pragma unroll
      for (int kw = 0; kw < 3; ++kw) {
        float xv = xt[ic][rr + kh][cc + kw];
        #pragma unroll
        for (int d = 0; d < 10; ++d)
          y[d] = fmaf(wl[(d * 20 + ic) * 9 + kh * 3 + kw], xv, y[d]);
      }
  float yr[10];
  #pragma unroll
  for (int d = 0; d < 10; ++d) yr[d] = fmaxf(y[d], 0.f);

  float al = alpha[0];
  int v = vp - 1;
  float x[10], h[10];
  #pragma unroll
  for (int d = 0; d < 10; ++d) {
    float s = 0.f;
    #pragma unroll
    for (int jj = 0; jj < 10; ++jj) s = fmaf(w2l[d * 10 + jj], yr[jj], s);
    float parts = fmaxf(s, 0.f);
    float xs = 0.f;
    #pragma unroll
    for (int ui = 0; ui < 5; ++ui)
      xs += msg_ws[(((size_t)(v * 5 + ui) * NB_ + n) * 10 + d) * HW_ + k];
    x[d] = parts + al * xs;
    h[d] = p_nodes[((size_t)(vp * NB_ + n) * 10 + d) * HW_ + k];
  }
  const float* gw = gru_gw + (size_t)vp * 40;
  const float* gb = gru_gb + (size_t)vp * 2;
  const float* cw = gru_cw + (size_t)vp * 200;
  float g0 = gb[0], g1 = gb[1];
  #pragma unroll
  for (int d = 0; d < 10; ++d) {
    g0 = fmaf(gw[d], x[d], fmaf(gw[10 + d], h[d], g0));
    g1 = fmaf(gw[20 + d], x[d], fmaf(gw[30 + d], h[d], g1));
  }
  float rg = sigmoidf_(g0);
  float ug = sigmoidf_(g1);
  #pragma unroll
  for (int d = 0; d < 10; ++d) {
    float s = 0.f;
    const float* cr = cw + d * 20;
    #pragma unroll
    for (int jj = 0; jj < 10; ++jj)
      s = fmaf(cr[jj], x[jj], fmaf(cr[10 + jj], rg * h[jj], s));
    float cn = fmaxf(s, 0.f);
    p_new[((size_t)(vp * NB_ + n) * 10 + d) * HW_ + k] = (1.f - ug) * h[d] + ug * cn;
  }
}

// ---------------------------------------------------------------------------
// K9: GRU for node 0
// ---------------------------------------------------------------------------
__global__ __launch_bounds__(256) void k_gru0(
    const float* __restrict__ h_nodes, const float* __restrict__ p_nodes,
    const float* __restrict__ gru_gw, const float* __restrict__ gru_gb,
    const float* __restrict__ gru_cw, float* __restrict__ p_new)
{
  int idx = blockIdx.x * 256 + threadIdx.x;
  if (idx >= NB_ * HW_) return;
  int n = idx / HW_, k = idx - n * HW_;
  float x[10], h[10];
  #pragma unroll
  for (int d = 0; d < 10; ++d) {
    x[d] = h_nodes[((size_t)n * 10 + d) * HW_ + k];
    h[d] = p_nodes[((size_t)n * 10 + d) * HW_ + k];
  }
  float g0 = gru_gb[0], g1 = gru_gb[1];
  #pragma unroll
  for (int d = 0; d < 10; ++d) {
    g0 = fmaf(gru_gw[d], x[d], fmaf(gru_gw[10 + d], h[d], g0));
    g1 = fmaf(gru_gw[20 + d], x[d], fmaf(gru_gw[30 + d], h[d], g1));
  }
  float rg = sigmoidf_(g0);
  float ug = sigmoidf_(g1);
  #pragma unroll
  for (int d = 0; d < 10; ++d) {
    float s = 0.f;
    const float* cr = gru_cw + d * 20;
    #pragma unroll
    for (int jj = 0; jj < 10; ++jj)
      s = fmaf(cr[jj], x[jj], fmaf(cr[10 + jj], rg * h[jj], s));
    float cn = fmaxf(s, 0.f);
    p_new[((size_t)n * 10 + d) * HW_ + k] = (1.f - ug) * h[d] + ug * cn;
  }
}

// ---------------------------------------------------------------------------
extern "C" void kernel_launch(void* const* d_in, const int* in_sizes, int n_in,
                              void* d_out, int out_size, void* d_ws, size_t ws_size,
                              hipStream_t stream) {
  (void)in_sizes; (void)n_in; (void)out_size; (void)ws_size;
  const float* h_nodes = (const float*)d_in[1];
  const float* p_nodes = (const float*)d_in[2];
  const float* xp      = (const float*)d_in[3];
  const float* h_att   = (const float*)d_in[4];
  const float* p_att   = (const float*)d_in[5];
  const float* dc_q_w  = (const float*)d_in[6];
  const float* dc_q_b  = (const float*)d_in[7];
  const float* dc_k_w  = (const float*)d_in[8];
  const float* dc_k_b  = (const float*)d_in[9];
  const float* dc_p_w  = (const float*)d_in[10];
  const float* dc_p_b  = (const float*)d_in[11];
  const float* ctx_w1  = (const float*)d_in[12];
  const float* ctx_w2  = (const float*)d_in[13];
  const float* ctx_b2  = (const float*)d_in[14];
  const float* du_a1   = (const float*)d_in[15];
  const float* du_a2   = (const float*)d_in[16];
  const float* du_a2b  = (const float*)d_in[17];
  const float* du_r1   = (const float*)d_in[18];
  const float* du_r2   = (const float*)d_in[19];
  const float* dl_a1   = (const float*)d_in[20];
  const float* dl_a2   = (const float*)d_in[21];
  const float* dl_a2b  = (const float*)d_in[22];
  const float* dl_r1   = (const float*)d_in[23];
  const float* dl_r2   = (const float*)d_in[24];
  const float* dp_proj = (const float*)d_in[25];
  const float* dp_r1   = (const float*)d_in[26];
  const float* dp_r2   = (const float*)d_in[27];
  const float* dp_r2b  = (const float*)d_in[28];
  const float* gru_gw  = (const float*)d_in[29];
  const float* gru_gb  = (const float*)d_in[30];
  const float* gru_cw  = (const float*)d_in[31];
  const float* alpha   = (const float*)d_in[32];

  float* ws = (float*)d_ws;
  float* keydot  = ws;                 // 4608
  float* qdot    = ws + 4608;          // 16
  float* dep_att = ws + 4624;          // 27648
  float* rpx     = ws + 32272;         // 46080
  float* att_sm  = ws + 78352;         // 138240
  float* da_u    = ws + 216592;        // 18432
  float* da_l    = ws + 235024;        // 9216
  float* yhv_ws  = ws + 244240;        // 276480 (old xpp slot)
  float* w0      = ws + 520720;        // 18432 -> floats end at 539152
  float* na_ws   = att_sm;             // alias (dead until k_heads)
  float* hu_ws   = att_sm + 27648;
  unsigned short* us = (unsigned short*)(ws + 539152);
  unsigned short* xbf = us;                       // 1,179,648 shorts
  unsigned short* wt  = us + 1179648;             // 4,718,592 shorts
  unsigned short* h1  = us + 5898240;             // 9,437,184 shorts
  float* msg_ws = (float*)(us + 5898240);         // alias h1 (dead after k_heads): 1,382,400 floats

  float* out      = (float*)d_out;
  float* out_pnew = out;               // 322560
  float* out_du   = out + 322560;      // 18432
  float* out_dl   = out + 340992;      // 9216
  float* out_fdep = out + 350208;      // 138240

  k_xbf<<<72, 256, 0, stream>>>(xp, xbf);
  k_wbf<<<2048, 256, 0, stream>>>(ctx_w1, du_a1, dl_a1, wt, w0);
  k_sm<<<12, 256, 0, stream>>>(p_att, na_ws);
  k_huc<<<192, 256, 0, stream>>>(xp, na_ws, hu_ws);
  k_qdot<<<12, 256, 0, stream>>>(na_ws, hu_ws, dc_q_w, dc_q_b, dc_p_w, qdot);
  k_keymma<<<18, 256, 0, stream>>>(xbf, dc_k_w, dc_k_b, dc_p_w, keydot);
  k_depatt<<<108, 256, 0, stream>>>(p_att, keydot, qdot, dc_p_b, dep_att);
  k_rpx<<<18, 256, 0, stream>>>(xp, dp_proj, rpx);
  k_convmma<<<576, 256, 0, stream>>>(xbf, wt, w0, dep_att, h_att, h1);
  k_heads<<<144, 256, 0, stream>>>(h1, ctx_w2, du_a2, dl_a2, ctx_b2, du_a2b, dl_a2b,
                                   out_fdep, out_du, out_dl, att_sm, da_u, da_l);
  k_yhv<<<108, 256, 0, stream>>>(p_nodes, dp_r1, yhv_ws);
  k_msgs_edge<<<540, 256, 0, stream>>>(att_sm, dep_att, rpx, yhv_ws,
                                       dp_r1, dp_r2, dp_r2b, msg_ws);
  k_parts_gru<<<108, 256, 0, stream>>>(h_nodes, p_nodes, h_att, da_u, da_l,
                                       du_r1, du_r2, dl_r1, dl_r2, msg_ws, alpha,
                                       gru_gw, gru_gb, gru_cw, out_pnew);
  k_gru0<<<18, 256, 0, stream>>>(h_nodes, p_nodes, gru_gw, gru_gb, gru_cw, out_pnew);
}

// Round 5
// 311.271 us; speedup vs baseline: 7.8924x; 1.2221x over previous
//
#include <hip/hip_runtime.h>
#include <math.h>

// Problem constants: N=2, C=256, H=W=48, HID=10, P=7
constexpr int NB_ = 2;
constexpr int C_  = 256;
constexpr int HW_ = 2304;   // 48*48

typedef float f32x4 __attribute__((ext_vector_type(4)));
typedef short short8 __attribute__((ext_vector_type(8)));

__device__ __forceinline__ float coordval(int c, int k) {
  int y = k / 48, x = k - y * 48;
  switch (c) {
    case 0: return x * (1.f/24.f) - 1.f;
    case 1: return y * (1.f/24.f) - 1.f;
    case 2: return (x + 1) * (1.f/24.f) - 1.f;
    case 3: return (y + 1) * (1.f/24.f) - 1.f;
    case 4: return (x + 0.5f) * (1.f/24.f) - 1.f;
    case 5: return (y + 0.5f) * (1.f/24.f) - 1.f;
    default: return 1.f/48.f;
  }
}

__device__ __forceinline__ float sigmoidf_(float x) { return 1.f / (1.f + expf(-x)); }
__device__ __forceinline__ unsigned short f2bf(float f) {
  unsigned int u = __float_as_uint(f);
  unsigned int r = (u + 0x7FFFu + ((u >> 16) & 1u)) >> 16;
  return (unsigned short)r;
}
__device__ __forceinline__ float bf2f(unsigned short h) {
  return __uint_as_float(((unsigned int)h) << 16);
}

// ---------------------------------------------------------------------------
// P1: xbf[n][y][x][c] = bf16(xp[n][c][y*48+x])   (NHWC bf16)
// ---------------------------------------------------------------------------
__global__ __launch_bounds__(256) void k_xbf(
    const float* __restrict__ xp, unsigned short* __restrict__ xbf)
{
  __shared__ float xt[64][65];
  int t = threadIdx.x;
  int px0 = blockIdx.x * 64;
  int n = px0 / HW_, k0 = px0 - n * HW_;
  for (int cb = 0; cb < 4; ++cb) {
    __syncthreads();
    for (int i = t; i < 4096; i += 256) {
      int cl = i >> 6, pxl = i & 63;
      xt[cl][pxl] = xp[((size_t)(n * C_ + cb * 64 + cl)) * HW_ + k0 + pxl];
    }
    __syncthreads();
    for (int i = t; i < 4096; i += 256) {
      int pxl = i >> 6, cl = i & 63;
      xbf[((size_t)(n * HW_ + k0 + pxl)) * 256 + cb * 64 + cl] = f2bf(xt[cl][pxl]);
    }
  }
}

// ---------------------------------------------------------------------------
// P2: weight transform to MFMA fragment order.
// wt frag addr: (((inst*9+pos)*8 + chunk)*16 + mf)*512 + lane*8 + j
//   where oc = mf*16 + (lane&15), c = chunk*32 + (lane>>4)*8 + j
// ---------------------------------------------------------------------------
__global__ __launch_bounds__(256) void k_wbf(
    const float* __restrict__ ctx_w1, const float* __restrict__ du_a1,
    const float* __restrict__ dl_a1,
    unsigned short* __restrict__ wt, float* __restrict__ w0)
{
  int inst = blockIdx.x >> 8, oc = blockIdx.x & 255;
  const float* src = (inst < 6) ? (ctx_w1 + (size_t)inst * 256 * 2313)
                   : (inst == 6 ? du_a1 : dl_a1);
  src += (size_t)oc * 2313;
  int mf = oc >> 4, lr = oc & 15;
  int t = threadIdx.x;
  for (int i = t; i < 2304; i += 256) {
    int pos = i >> 8, c = i & 255;
    float v = src[(size_t)(c + 1) * 9 + pos];
    int chunk = c >> 5, lg = (c >> 3) & 3, j = c & 7;
    size_t addr = ((((size_t)(inst * 9 + pos) * 8 + chunk) * 16 + mf) << 9)
                  + (size_t)(lg * 16 + lr) * 8 + j;
    wt[addr] = f2bf(v);
  }
  if (t < 9) w0[((size_t)inst * 256 + oc) * 9 + t] = src[t];
}

// ---------------------------------------------------------------------------
// K1: keydot via MFMA
// ---------------------------------------------------------------------------
__global__ __launch_bounds__(256) void k_keymma(
    const unsigned short* __restrict__ xbf, const float* __restrict__ dc_k_w,
    const float* __restrict__ dc_k_b, const float* __restrict__ dc_p_w,
    float* __restrict__ keydot)
{
  __shared__ unsigned short wlf[64 * 296];
  __shared__ unsigned short xl[256 * 40];
  int t = threadIdx.x;
  for (int i = t; i < 64 * 264; i += 256) {
    int d = i / 264, c = i - d * 264;
    wlf[d * 296 + c] = f2bf(dc_k_w[i]);
  }
  for (int i = t; i < 64 * 32; i += 256) {
    int d = i >> 5, c = 264 + (i & 31);
    wlf[d * 296 + c] = 0;
  }
  int px0 = blockIdx.x * 256;
  int w = t >> 6, l = t & 63;
  int lr = l & 15, lg = l >> 4;

  f32x4 acc[4][4];
  #pragma unroll
  for (int mi = 0; mi < 4; ++mi)
    #pragma unroll
    for (int nf = 0; nf < 4; ++nf) acc[mi][nf] = (f32x4){0.f,0.f,0.f,0.f};

  for (int ch = 0; ch < 9; ++ch) {
    __syncthreads();
    for (int i = t; i < 1024; i += 256) {
      int pxl = i >> 2, q = i & 3;
      int px = px0 + pxl, n = px / HW_, k = px - n * HW_;
      int c0 = ch * 32 + q * 8;
      short8 v;
      if (c0 + 7 < 256) {
        v = *(const short8*)(xbf + ((size_t)(n * HW_ + k)) * 256 + c0);
      } else {
        #pragma unroll
        for (int j = 0; j < 8; ++j) {
          int cc = c0 + j;
          float f = (cc < 256) ? bf2f(xbf[((size_t)(n * HW_ + k)) * 256 + cc])
                   : (cc < 264 ? coordval(cc - 256, k) : 0.f);
          v[j] = (short)f2bf(f);
        }
      }
      *(short8*)(xl + pxl * 40 + q * 8) = v;
    }
    __syncthreads();
    short8 bfr[4];
    #pragma unroll
    for (int nf = 0; nf < 4; ++nf)
      bfr[nf] = *(const short8*)(xl + (w * 64 + nf * 16 + lr) * 40 + lg * 8);
    #pragma unroll
    for (int mi = 0; mi < 4; ++mi) {
      short8 a = *(const short8*)(wlf + (mi * 16 + lr) * 296 + ch * 32 + lg * 8);
      #pragma unroll
      for (int nf = 0; nf < 4; ++nf)
        acc[mi][nf] = __builtin_amdgcn_mfma_f32_16x16x32_bf16(a, bfr[nf], acc[mi][nf], 0, 0, 0);
    }
  }

  #pragma unroll
  for (int nf = 0; nf < 4; ++nf) {
    float s = 0.f;
    #pragma unroll
    for (int mi = 0; mi < 4; ++mi)
      #pragma unroll
      for (int r = 0; r < 4; ++r) {
        int d = mi * 16 + lg * 4 + r;
        s += dc_p_w[64 + d] * fmaxf(acc[mi][nf][r] + dc_k_b[d], 0.f);
      }
    s += __shfl_down(s, 32, 64);
    s += __shfl_down(s, 16, 64);
    if (lg == 0) keydot[px0 + w * 64 + nf * 16 + lr] = s;
  }
}

// ---------------------------------------------------------------------------
// K2a: na softmax
// ---------------------------------------------------------------------------
__global__ __launch_bounds__(256) void k_sm(
    const float* __restrict__ p_att, float* __restrict__ na_ws)
{
  __shared__ float red[16];
  int t = threadIdx.x;
  const float* att = p_att + (size_t)(NB_ + blockIdx.x) * HW_;
  float* na = na_ws + (size_t)blockIdx.x * HW_;

  float m = -1e30f;
  for (int k = t; k < HW_; k += 256) m = fmaxf(m, att[k]);
  #pragma unroll
  for (int off = 32; off > 0; off >>= 1) m = fmaxf(m, __shfl_down(m, off, 64));
  if ((t & 63) == 0) red[t >> 6] = m;
  __syncthreads();
  if (t == 0) { float mm = red[0]; for (int w = 1; w < 4; ++w) mm = fmaxf(mm, red[w]); red[0] = mm; }
  __syncthreads();
  m = red[0];
  float s = 0.f;
  for (int k = t; k < HW_; k += 256) s += expf(att[k] - m);
  #pragma unroll
  for (int off = 32; off > 0; off >>= 1) s += __shfl_down(s, off, 64);
  if ((t & 63) == 0) red[8 + (t >> 6)] = s;
  __syncthreads();
  if (t == 0) { float ss = 0; for (int w = 0; w < 4; ++w) ss += red[8 + w]; red[8] = ss; }
  __syncthreads();
  float inv = 1.f / red[8];
  for (int k = t; k < HW_; k += 256) na[k] = expf(att[k] - m) * inv;
}

// ---------------------------------------------------------------------------
// K2b: hu[pair][c]
// ---------------------------------------------------------------------------
__global__ __launch_bounds__(256) void k_huc(
    const float* __restrict__ xp, const float* __restrict__ na_ws,
    float* __restrict__ hu_ws)
{
  __shared__ float na[HW_];
  int b = blockIdx.x;
  int cb = b & 15; int pair = b >> 4;
  int n = pair % NB_;
  int t = threadIdx.x;
  const float* nag = na_ws + (size_t)pair * HW_;
  for (int k = t; k < HW_; k += 256) na[k] = nag[k];
  __syncthreads();
  int wv = t >> 6, l = t & 63;
  #pragma unroll
  for (int cq = 0; cq < 4; ++cq) {
    int c = cb * 16 + wv * 4 + cq;
    const float* x = xp + (size_t)(n * C_ + c) * HW_;
    float a = 0.f;
    for (int k = l; k < HW_; k += 64) a = fmaf(x[k], na[k], a);
    #pragma unroll
    for (int off = 32; off > 0; off >>= 1) a += __shfl_down(a, off, 64);
    if (l == 0) hu_ws[(size_t)pair * 256 + c] = a;
  }
}

// ---------------------------------------------------------------------------
// K2c: co + q + qdot
// ---------------------------------------------------------------------------
__global__ __launch_bounds__(256) void k_qdot(
    const float* __restrict__ na_ws, const float* __restrict__ hu_ws,
    const float* __restrict__ dc_q_w, const float* __restrict__ dc_q_b,
    const float* __restrict__ dc_p_w, float* __restrict__ qdot)
{
  __shared__ float na[HW_];
  __shared__ float co[8];
  __shared__ float hu[256];
  __shared__ float ql[64];
  int t = threadIdx.x;
  int pair = blockIdx.x;
  const float* nag = na_ws + (size_t)pair * HW_;
  for (int k = t; k < HW_; k += 256) na[k] = nag[k];
  hu[t] = hu_ws[(size_t)pair * 256 + t];
  __syncthreads();
  int wv = t >> 6, l = t & 63;
  #pragma unroll
  for (int q = 0; q < 2; ++q) {
    int cc = wv * 2 + q;
    float a = 0.f;
    for (int k = l; k < HW_; k += 64) a = fmaf(coordval(cc, k), na[k], a);
    #pragma unroll
    for (int off = 32; off > 0; off >>= 1) a += __shfl_down(a, off, 64);
    if (l == 0) co[cc] = a;
  }
  __syncthreads();
  if (t < 64) {
    float a = dc_q_b[t];
    const float* wr = dc_q_w + (size_t)t * 264;
    for (int c = 0; c < 256; ++c) a = fmaf(wr[c], hu[c], a);
    #pragma unroll
    for (int c = 0; c < 8; ++c) a = fmaf(wr[256 + c], co[c], a);
    ql[t] = fmaxf(a, 0.f) * dc_p_w[t];
  }
  __syncthreads();
  if (t == 0) {
    float a = 0.f;
    for (int d = 0; d < 64; ++d) a += ql[d];
    qdot[pair] = a;
  }
}

// ---------------------------------------------------------------------------
// K3: dep_att
// ---------------------------------------------------------------------------
__global__ __launch_bounds__(256) void k_depatt(
    const float* __restrict__ p_att, const float* __restrict__ keydot,
    const float* __restrict__ qdot, const float* __restrict__ dc_p_b,
    float* __restrict__ dep_att)
{
  int idx = blockIdx.x * 256 + threadIdx.x;
  if (idx >= 6 * NB_ * HW_) return;
  int e = idx / (NB_ * HW_); int r = idx - e * NB_ * HW_;
  int n = r / HW_, k = r - n * HW_;
  float energy = qdot[e * NB_ + n] + keydot[n * HW_ + k] + dc_p_b[0];
  float a = sigmoidf_(energy);
  float hu = p_att[(size_t)((1 + e) * NB_ + n) * HW_ + k];
  dep_att[idx] = a * (1.f - hu);
}

// ---------------------------------------------------------------------------
// K4: rpx from xbf, 4-way channel split, 72 blocks
// ---------------------------------------------------------------------------
__global__ __launch_bounds__(256) void k_rpx(
    const unsigned short* __restrict__ xbf, const float* __restrict__ dp_proj,
    float* __restrict__ rpx)
{
  __shared__ float pj[2560];          // [c][d]
  __shared__ float part[3 * 64 * 10];
  int t = threadIdx.x;
  for (int i = t; i < 2560; i += 256) {
    int d = i >> 8, c = i & 255;
    pj[c * 10 + d] = dp_proj[i];
  }
  __syncthreads();
  int lane = t & 63, q = t >> 6;
  int px = blockIdx.x * 64 + lane;
  const unsigned short* xr = xbf + (size_t)px * 256;
  float acc[10];
  #pragma unroll
  for (int d = 0; d < 10; ++d) acc[d] = 0.f;
  for (int c8 = q * 8; c8 < q * 8 + 8; ++c8) {
    short8 v = *(const short8*)(xr + c8 * 8);
    #pragma unroll
    for (int j = 0; j < 8; ++j) {
      float f = bf2f((unsigned short)v[j]);
      const float* pc = &pj[(c8 * 8 + j) * 10];
      #pragma unroll
      for (int d = 0; d < 10; ++d) acc[d] = fmaf(pc[d], f, acc[d]);
    }
  }
  if (q) {
    #pragma unroll
    for (int d = 0; d < 10; ++d) part[((q - 1) * 64 + lane) * 10 + d] = acc[d];
  }
  __syncthreads();
  if (t < 64) {
    int p2 = blockIdx.x * 64 + t;
    int n = p2 / HW_, k = p2 - n * HW_;
    #pragma unroll
    for (int d = 0; d < 10; ++d) {
      float s = acc[d] + part[t * 10 + d] + part[(64 + t) * 10 + d] + part[(128 + t) * 10 + d];
      rpx[((size_t)(n * 10 + d)) * HW_ + k] = fmaxf(s, 0.f);
    }
  }
}

// ---------------------------------------------------------------------------
// K5: fused conv+head. Block = 256 oc x 64 px (8x8 tile), 4 waves (wave=wm).
// Full halo (10x10x256 bf16, XOR-swizzled) staged once; no in-loop barriers.
// Epilogue: +att-channel conv, relu, fused 1x1 head + bias + softmax.
// grid 576: inst = bid&7 (XCD-pinned), n = (bid>>3)&1, tile = bid>>4 (6x6).
// ---------------------------------------------------------------------------
__global__ __launch_bounds__(256) void k_convfused(
    const unsigned short* __restrict__ xbf, const unsigned short* __restrict__ wt,
    const float* __restrict__ w0, const float* __restrict__ dep_att,
    const float* __restrict__ h_att,
    const float* __restrict__ ctx_w2, const float* __restrict__ du_a2,
    const float* __restrict__ dl_a2,
    const float* __restrict__ ctx_b2, const float* __restrict__ du_a2b,
    const float* __restrict__ dl_a2b,
    float* __restrict__ out_fdep, float* __restrict__ out_du, float* __restrict__ out_dl,
    float* __restrict__ att_sm, float* __restrict__ da_u, float* __restrict__ da_l)
{
  int bid = blockIdx.x;
  int inst = bid & 7;
  int n = (bid >> 3) & 1;
  int tile = bid >> 4;
  int ty0 = (tile / 6) * 8, tx0 = (tile % 6) * 8;

  __shared__ unsigned short xs[100 * 256];  // 10x10 halo x 256ch, swizzled
  __shared__ float asf[100];
  __shared__ float w0l[2304];
  __shared__ float w2l[1280];
  __shared__ float sred[1280];              // [wm*4+nf][lr][d]

  const float* asrc = (inst < 6) ? dep_att + (size_t)(inst * NB_ + n) * HW_
                    : h_att + (size_t)(((inst == 6) ? 1 : 2) * NB_ + n) * HW_;
  int nd = (inst < 6) ? 5 : (inst == 6 ? 4 : 2);
  const float* w2 = (inst < 6) ? ctx_w2 + (size_t)inst * 5 * 256
                               : (inst == 6 ? du_a2 : dl_a2);

  int t = threadIdx.x;
  const unsigned short* xg = xbf + (size_t)n * HW_ * 256;
  // stage halo (swizzled slot = q ^ (row&7))
  for (int i = t; i < 3200; i += 256) {
    int row = i >> 5, q = i & 31;
    int yy = row / 10, xx = row - yy * 10;
    int gy = ty0 + yy - 1, gx = tx0 + xx - 1;
    short8 v = (short8){0,0,0,0,0,0,0,0};
    if (gy >= 0 && gy < 48 && gx >= 0 && gx < 48)
      v = *(const short8*)(xg + ((size_t)(gy * 48 + gx)) * 256 + q * 8);
    int s = q ^ (row & 7);
    *(short8*)(xs + row * 256 + s * 8) = v;
  }
  for (int i = t; i < 100; i += 256) {
    int yy = i / 10, xx = i - yy * 10;
    int gy = ty0 + yy - 1, gx = tx0 + xx - 1;
    asf[i] = (gy >= 0 && gy < 48 && gx >= 0 && gx < 48) ? asrc[gy * 48 + gx] : 0.f;
  }
  for (int i = t; i < 2304; i += 256) w0l[i] = w0[(size_t)inst * 2304 + i];
  for (int i = t; i < 1280; i += 256) w2l[i] = (i < nd * 256) ? w2[i] : 0.f;
  __syncthreads();

  int wm = t >> 6, l = t & 63;
  int lr = l & 15, lg = l >> 4;

  f32x4 acc[4][4];
  #pragma unroll
  for (int mi = 0; mi < 4; ++mi)
    #pragma unroll
    for (int nf = 0; nf < 4; ++nf) acc[mi][nf] = (f32x4){0.f,0.f,0.f,0.f};

  const unsigned short* wta = wt + (((size_t)inst * 72 * 16) << 9)
                              + (((size_t)(wm * 4)) << 9) + (size_t)l * 8;
  short8 av[4], nv[4];
  #pragma unroll
  for (int mi = 0; mi < 4; ++mi)
    av[mi] = *(const short8*)(wta + ((size_t)mi << 9));

  for (int chunk = 0; chunk < 8; ++chunk) {
    #pragma unroll
    for (int pos = 0; pos < 9; ++pos) {
      int kh = pos / 3, kw = pos - kh * 3;
      // prefetch next-pos A frags
      {
        int nch = (pos == 8) ? chunk + 1 : chunk;
        if (nch > 7) nch = 7;
        int npos = (pos == 8) ? 0 : pos + 1;
        size_t ofs = ((size_t)(npos * 8 + nch) * 16) << 9;
        #pragma unroll
        for (int mi = 0; mi < 4; ++mi)
          nv[mi] = *(const short8*)(wta + ofs + ((size_t)mi << 9));
      }
      short8 bfr[4];
      #pragma unroll
      for (int nf = 0; nf < 4; ++nf) {
        int p = nf * 16 + lr;
        int y = p >> 3, x = p & 7;
        int rowIdx = (y + kh) * 10 + (x + kw);
        int s = (chunk * 4 + lg) ^ (rowIdx & 7);
        bfr[nf] = *(const short8*)(xs + rowIdx * 256 + s * 8);
      }
      #pragma unroll
      for (int mi = 0; mi < 4; ++mi)
        #pragma unroll
        for (int nf = 0; nf < 4; ++nf)
          acc[mi][nf] = __builtin_amdgcn_mfma_f32_16x16x32_bf16(av[mi], bfr[nf], acc[mi][nf], 0, 0, 0);
      #pragma unroll
      for (int mi = 0; mi < 4; ++mi) av[mi] = nv[mi];
    }
  }

  // epilogue: att-channel conv + relu + head partials
  float pd[4][5];
  #pragma unroll
  for (int nf = 0; nf < 4; ++nf)
    #pragma unroll
    for (int d = 0; d < 5; ++d) pd[nf][d] = 0.f;

  #pragma unroll
  for (int nf = 0; nf < 4; ++nf) {
    int p = nf * 16 + lr;
    int y = p >> 3, x = p & 7;
    #pragma unroll
    for (int mi = 0; mi < 4; ++mi) {
      #pragma unroll
      for (int r = 0; r < 4; ++r) {
        int oc = wm * 64 + mi * 16 + lg * 4 + r;
        float v = acc[mi][nf][r];
        const float* wr = &w0l[oc * 9];
        #pragma unroll
        for (int pos = 0; pos < 9; ++pos) {
          int kh = pos / 3, kw = pos - kh * 3;
          v = fmaf(wr[pos], asf[(y + kh) * 10 + (x + kw)], v);
        }
        v = fmaxf(v, 0.f);
        #pragma unroll
        for (int d = 0; d < 5; ++d) pd[nf][d] = fmaf(w2l[d * 256 + oc], v, pd[nf][d]);
      }
    }
  }
  #pragma unroll
  for (int nf = 0; nf < 4; ++nf)
    #pragma unroll
    for (int d = 0; d < 5; ++d) {
      float s = pd[nf][d];
      s += __shfl_down(s, 32, 64);
      s += __shfl_down(s, 16, 64);
      pd[nf][d] = s;
    }
  if (lg == 0) {
    #pragma unroll
    for (int nf = 0; nf < 4; ++nf)
      #pragma unroll
      for (int d = 0; d < 5; ++d)
        sred[((wm * 4 + nf) * 16 + lr) * 5 + d] = pd[nf][d];
  }
  __syncthreads();
  if (t < 64) {
    int nf = t >> 4, lr2 = t & 15;
    int y = t >> 3, x = t & 7;
    int gk = (ty0 + y) * 48 + tx0 + x;
    float vals[5];
    float mx = -1e30f;
    for (int d = 0; d < nd; ++d) {
      float s = 0.f;
      #pragma unroll
      for (int w = 0; w < 4; ++w) s += sred[((w * 4 + nf) * 16 + lr2) * 5 + d];
      s += (inst < 6) ? ctx_b2[inst * 5 + d] : (inst == 6 ? du_a2b[d] : dl_a2b[d]);
      vals[d] = s;
      mx = fmaxf(mx, s);
      if (inst < 6)       out_fdep[((size_t)(inst * NB_ + n) * 5 + d) * HW_ + gk] = s;
      else if (inst == 6) out_du[((size_t)n * 4 + d) * HW_ + gk] = s;
      else                out_dl[((size_t)n * 2 + d) * HW_ + gk] = s;
    }
    float ssum = 0.f;
    for (int d = 0; d < nd; ++d) { vals[d] = expf(vals[d] - mx); ssum += vals[d]; }
    float is = 1.f / ssum;
    for (int d = 0; d < nd; ++d) {
      float sm = vals[d] * is;
      if (inst < 6)       att_sm[((size_t)(inst * NB_ + n) * 5 + d) * HW_ + gk] = sm;
      else if (inst == 6) da_u[((size_t)n * 4 + d) * HW_ + gk] = sm;
      else                da_l[((size_t)n * 2 + d) * HW_ + gk] = sm;
    }
  }
}

// ---------------------------------------------------------------------------
// K7a: yhv
// ---------------------------------------------------------------------------
__global__ __launch_bounds__(256) void k_yhv(
    const float* __restrict__ p_nodes, const float* __restrict__ dp_r1,
    float* __restrict__ yhv_ws)
{
  int b = blockIdx.x;
  int tile = b % 9; b /= 9;
  int n = b % NB_;  int v = b / NB_;
  int ty0 = (tile / 3) * 16, tx0 = (tile % 3) * 16;
  __shared__ float xt[10][18][20];
  __shared__ float wl[900];
  int t = threadIdx.x;
  for (int i = t; i < 900; i += 256) {
    int d = i / 90; int rest = i - d * 90; int ic = rest / 9; int pos = rest - ic * 9;
    wl[i] = dp_r1[(d * 20 + 10 + ic) * 9 + pos];
  }
  for (int i = t; i < 10 * 324; i += 256) {
    int d = i / 324; int rr = (i % 324) / 18; int cc = i % 18;
    int gy = ty0 + rr - 1, gx = tx0 + cc - 1;
    float val = 0.f;
    if (gy >= 0 && gy < 48 && gx >= 0 && gx < 48)
      val = p_nodes[((size_t)(v * NB_ + n) * 10 + d) * HW_ + gy * 48 + gx];
    xt[d][rr][cc] = val;
  }
  __syncthreads();
  int rr = t >> 4, cc = t & 15;
  int k = (ty0 + rr) * 48 + tx0 + cc;
  float y[10];
  #pragma unroll
  for (int d = 0; d < 10; ++d) y[d] = 0.f;
  for (int ic = 0; ic < 10; ++ic)
    #pragma unroll
    for (int kh = 0; kh < 3; ++kh)
      #pragma unroll
      for (int kw = 0; kw < 3; ++kw) {
        float xv = xt[ic][rr + kh][cc + kw];
        #pragma unroll
        for (int d = 0; d < 10; ++d)
          y[d] = fmaf(wl[(d * 10 + ic) * 9 + kh * 3 + kw], xv, y[d]);
      }
  #pragma unroll
  for (int d = 0; d < 10; ++d)
    yhv_ws[((size_t)(v * NB_ + n) * 10 + d) * HW_ + k] = y[d];
}

// ---------------------------------------------------------------------------
// K7b: per-edge message
// ---------------------------------------------------------------------------
__global__ __launch_bounds__(256) void k_msgs_edge(
    const float* __restrict__ att_sm, const float* __restrict__ dep_att,
    const float* __restrict__ rpx, const float* __restrict__ yhv_ws,
    const float* __restrict__ dp_r1, const float* __restrict__ dp_r2,
    const float* __restrict__ dp_r2b, float* __restrict__ msg_ws)
{
  int b = blockIdx.x;
  int tile = b % 9; b /= 9;
  int n = b % NB_;  b /= NB_;
  int ui = b % 5;   int v = b / 5;
  int u = (ui < v) ? ui : ui + 1;
  int ce = (v < u) ? v : v - 1;
  int ty0 = (tile / 3) * 16, tx0 = (tile % 3) * 16;

  __shared__ float xt[10][18][20];
  __shared__ float wl[900];
  __shared__ float w2l[100];
  __shared__ float b2l[10];
  int t = threadIdx.x;
  for (int i = t; i < 900; i += 256) {
    int d = i / 90; int rest = i - d * 90; int ic = rest / 9; int pos = rest - ic * 9;
    wl[i] = dp_r1[(d * 20 + ic) * 9 + pos];
  }
  for (int i = t; i < 100; i += 256) w2l[i] = dp_r2[i];
  if (t < 10) b2l[t] = dp_r2b[t];

  const float* asrc = att_sm + ((size_t)(u * NB_ + n) * 5 + ce) * HW_;
  const float* dsrc = dep_att + (size_t)(u * NB_ + n) * HW_;
  for (int i = t; i < 10 * 324; i += 256) {
    int d = i / 324; int rr = (i % 324) / 18; int cc = i % 18;
    int gy = ty0 + rr - 1, gx = tx0 + cc - 1;
    float val = 0.f;
    if (gy >= 0 && gy < 48 && gx >= 0 && gx < 48) {
      int kk = gy * 48 + gx;
      val = asrc[kk] * dsrc[kk] * rpx[((size_t)n * 10 + d) * HW_ + kk];
    }
    xt[d][rr][cc] = val;
  }
  __syncthreads();
  int rr = t >> 4, cc = t & 15;
  int k = (ty0 + rr) * 48 + tx0 + cc;
  float y[10];
  #pragma unroll
  for (int d = 0; d < 10; ++d) y[d] = 0.f;
  for (int ic = 0; ic < 10; ++ic)
    #pragma unroll
    for (int kh = 0; kh < 3; ++kh)
      #pragma unroll
      for (int kw = 0; kw < 3; ++kw) {
        float xv = xt[ic][rr + kh][cc + kw];
        #pragma unroll
        for (int d = 0; d < 10; ++d)
          y[d] = fmaf(wl[(d * 10 + ic) * 9 + kh * 3 + kw], xv, y[d]);
      }
  float s[10];
  #pragma unroll
  for (int d = 0; d < 10; ++d)
    s[d] = fmaxf(y[d] + yhv_ws[((size_t)(v * NB_ + n) * 10 + d) * HW_ + k], 0.f);
  #pragma unroll
  for (int d = 0; d < 10; ++d) {
    float m = b2l[d];
    #pragma unroll
    for (int j = 0; j < 10; ++j) m = fmaf(w2l[d * 10 + j], s[j], m);
    msg_ws[(((size_t)(v * 5 + ui) * NB_ + n) * 10 + d) * HW_ + k] = sigmoidf_(m);
  }
}

// ---------------------------------------------------------------------------
// K8: parts conv + alpha*sum(msgs) + GRU
// ---------------------------------------------------------------------------
__global__ __launch_bounds__(256) void k_parts_gru(
    const float* __restrict__ h_nodes, const float* __restrict__ p_nodes,
    const float* __restrict__ h_att,
    const float* __restrict__ da_u, const float* __restrict__ da_l,
    const float* __restrict__ du_r1, const float* __restrict__ du_r2,
    const float* __restrict__ dl_r1, const float* __restrict__ dl_r2,
    const float* __restrict__ msg_ws, const float* __restrict__ alpha,
    const float* __restrict__ gru_gw, const float* __restrict__ gru_gb,
    const float* __restrict__ gru_cw, float* __restrict__ p_new)
{
  int b = blockIdx.x;
  int tile = b % 9; b /= 9;
  int n = b % NB_;  int vp = b / NB_ + 1;
  int ty0 = (tile / 3) * 16, tx0 = (tile % 3) * 16;
  bool isU = (vp <= 4);
  int j = isU ? vp - 1 : vp - 5;
  const float* parent = h_nodes + ((size_t)((isU ? 1 : 2) * NB_ + n) * 10) * HW_;
  const float* patt   = h_att + (size_t)((isU ? 1 : 2) * NB_ + n) * HW_;
  const float* da     = isU ? (da_u + ((size_t)n * 4 + j) * HW_) : (da_l + ((size_t)n * 2 + j) * HW_);
  const float* child  = p_nodes + (size_t)(vp * NB_ + n) * 10 * HW_;
  const float* r1 = isU ? du_r1 : dl_r1;
  const float* r2 = isU ? du_r2 : dl_r2;

  __shared__ float xt[20][18][20];
  __shared__ float wl[1800];
  __shared__ float w2l[100];
  int t = threadIdx.x;
  for (int i = t; i < 1800; i += 256) wl[i] = r1[i];
  for (int i = t; i < 100; i += 256) w2l[i] = r2[i];
  for (int i = t; i < 20 * 324; i += 256) {
    int d = i / 324; int rr = (i % 324) / 18; int cc = i % 18;
    int gy = ty0 + rr - 1, gx = tx0 + cc - 1;
    float val = 0.f;
    if (gy >= 0 && gy < 48 && gx >= 0 && gx < 48) {
      int kk = gy * 48 + gx;
      val = (d < 10) ? parent[(size_t)d * HW_ + kk] * da[kk] * patt[kk]
                     : child[(size_t)(d - 10) * HW_ + kk];
    }
    xt[d][rr][cc] = val;
  }
  __syncthreads();
  int rr = t >> 4, cc = t & 15;
  int k = (ty0 + rr) * 48 + tx0 + cc;
  float y[10];
  #pragma unroll
  for (int d = 0; d < 10; ++d) y[d] = 0.f;
  for (int ic = 0; ic < 20; ++ic)
    #pragma unroll
    for (int kh = 0; kh < 3; ++kh)
      #pragma unroll
      for (int kw = 0; kw < 3; ++kw) {
        float xv = xt[ic][rr + kh][cc + kw];
        #pragma unroll
        for (int d = 0; d < 10; ++d)
          y[d] = fmaf(wl[(d * 20 + ic) * 9 + kh * 3 + kw], xv, y[d]);
      }
  float yr[10];
  #pragma unroll
  for (int d = 0; d < 10; ++d) yr[d] = fmaxf(y[d], 0.f);

  float al = alpha[0];
  int v = vp - 1;
  float x[10], h[10];
  #pragma unroll
  for (int d = 0; d < 10; ++d) {
    float s = 0.f;
    #pragma unroll
    for (int jj = 0; jj < 10; ++jj) s = fmaf(w2l[d * 10 + jj], yr[jj], s);
    float parts = fmaxf(s, 0.f);
    float xs = 0.f;
    #pragma unroll
    for (int ui = 0; ui < 5; ++ui)
      xs += msg_ws[(((size_t)(v * 5 + ui) * NB_ + n) * 10 + d) * HW_ + k];
    x[d] = parts + al * xs;
    h[d] = p_nodes[((size_t)(vp * NB_ + n) * 10 + d) * HW_ + k];
  }
  const float* gw = gru_gw + (size_t)vp * 40;
  const float* gb = gru_gb + (size_t)vp * 2;
  const float* cw = gru_cw + (size_t)vp * 200;
  float g0 = gb[0], g1 = gb[1];
  #pragma unroll
  for (int d = 0; d < 10; ++d) {
    g0 = fmaf(gw[d], x[d], fmaf(gw[10 + d], h[d], g0));
    g1 = fmaf(gw[20 + d], x[d], fmaf(gw[30 + d], h[d], g1));
  }
  float rg = sigmoidf_(g0);
  float ug = sigmoidf_(g1);
  #pragma unroll
  for (int d = 0; d < 10; ++d) {
    float s = 0.f;
    const float* cr = cw + d * 20;
    #pragma unroll
    for (int jj = 0; jj < 10; ++jj)
      s = fmaf(cr[jj], x[jj], fmaf(cr[10 + jj], rg * h[jj], s));
    float cn = fmaxf(s, 0.f);
    p_new[((size_t)(vp * NB_ + n) * 10 + d) * HW_ + k] = (1.f - ug) * h[d] + ug * cn;
  }
}

// ---------------------------------------------------------------------------
// K9: GRU node 0
// ---------------------------------------------------------------------------
__global__ __launch_bounds__(256) void k_gru0(
    const float* __restrict__ h_nodes, const float* __restrict__ p_nodes,
    const float* __restrict__ gru_gw, const float* __restrict__ gru_gb,
    const float* __restrict__ gru_cw, float* __restrict__ p_new)
{
  int idx = blockIdx.x * 256 + threadIdx.x;
  if (idx >= NB_ * HW_) return;
  int n = idx / HW_, k = idx - n * HW_;
  float x[10], h[10];
  #pragma unroll
  for (int d = 0; d < 10; ++d) {
    x[d] = h_nodes[((size_t)n * 10 + d) * HW_ + k];
    h[d] = p_nodes[((size_t)n * 10 + d) * HW_ + k];
  }
  float g0 = gru_gb[0], g1 = gru_gb[1];
  #pragma unroll
  for (int d = 0; d < 10; ++d) {
    g0 = fmaf(gru_gw[d], x[d], fmaf(gru_gw[10 + d], h[d], g0));
    g1 = fmaf(gru_gw[20 + d], x[d], fmaf(gru_gw[30 + d], h[d], g1));
  }
  float rg = sigmoidf_(g0);
  float ug = sigmoidf_(g1);
  #pragma unroll
  for (int d = 0; d < 10; ++d) {
    float s = 0.f;
    const float* cr = gru_cw + d * 20;
    #pragma unroll
    for (int jj = 0; jj < 10; ++jj)
      s = fmaf(cr[jj], x[jj], fmaf(cr[10 + jj], rg * h[jj], s));
    float cn = fmaxf(s, 0.f);
    p_new[((size_t)n * 10 + d) * HW_ + k] = (1.f - ug) * h[d] + ug * cn;
  }
}

// ---------------------------------------------------------------------------
extern "C" void kernel_launch(void* const* d_in, const int* in_sizes, int n_in,
                              void* d_out, int out_size, void* d_ws, size_t ws_size,
                              hipStream_t stream) {
  (void)in_sizes; (void)n_in; (void)out_size; (void)ws_size;
  const float* h_nodes = (const float*)d_in[1];
  const float* p_nodes = (const float*)d_in[2];
  const float* xp      = (const float*)d_in[3];
  const float* h_att   = (const float*)d_in[4];
  const float* p_att   = (const float*)d_in[5];
  const float* dc_q_w  = (const float*)d_in[6];
  const float* dc_q_b  = (const float*)d_in[7];
  const float* dc_k_w  = (const float*)d_in[8];
  const float* dc_k_b  = (const float*)d_in[9];
  const float* dc_p_w  = (const float*)d_in[10];
  const float* dc_p_b  = (const float*)d_in[11];
  const float* ctx_w1  = (const float*)d_in[12];
  const float* ctx_w2  = (const float*)d_in[13];
  const float* ctx_b2  = (const float*)d_in[14];
  const float* du_a1   = (const float*)d_in[15];
  const float* du_a2   = (const float*)d_in[16];
  const float* du_a2b  = (const float*)d_in[17];
  const float* du_r1   = (const float*)d_in[18];
  const float* du_r2   = (const float*)d_in[19];
  const float* dl_a1   = (const float*)d_in[20];
  const float* dl_a2   = (const float*)d_in[21];
  const float* dl_a2b  = (const float*)d_in[22];
  const float* dl_r1   = (const float*)d_in[23];
  const float* dl_r2   = (const float*)d_in[24];
  const float* dp_proj = (const float*)d_in[25];
  const float* dp_r1   = (const float*)d_in[26];
  const float* dp_r2   = (const float*)d_in[27];
  const float* dp_r2b  = (const float*)d_in[28];
  const float* gru_gw  = (const float*)d_in[29];
  const float* gru_gb  = (const float*)d_in[30];
  const float* gru_cw  = (const float*)d_in[31];
  const float* alpha   = (const float*)d_in[32];

  float* ws = (float*)d_ws;
  float* keydot  = ws;                 // 4608
  float* qdot    = ws + 4608;          // 16
  float* dep_att = ws + 4624;          // 27648
  float* rpx     = ws + 32272;         // 46080
  float* att_sm  = ws + 78352;         // 138240
  float* da_u    = ws + 216592;        // 18432
  float* da_l    = ws + 235024;        // 9216
  float* yhv_ws  = ws + 244240;        // 276480
  float* w0      = ws + 520720;        // 18432 -> floats end at 539152
  float* na_ws   = att_sm;             // alias (dead until k_convfused)
  float* hu_ws   = att_sm + 27648;
  unsigned short* us = (unsigned short*)(ws + 539152);
  unsigned short* xbf = us;                       // 1,179,648 shorts
  unsigned short* wt  = us + 1179648;             // 4,718,592 shorts
  float* msg_ws = (float*)(us + 5898240);         // 1,382,400 floats

  float* out      = (float*)d_out;
  float* out_pnew = out;               // 322560
  float* out_du   = out + 322560;      // 18432
  float* out_dl   = out + 340992;      // 9216
  float* out_fdep = out + 350208;      // 138240

  k_xbf<<<72, 256, 0, stream>>>(xp, xbf);
  k_wbf<<<2048, 256, 0, stream>>>(ctx_w1, du_a1, dl_a1, wt, w0);
  k_sm<<<12, 256, 0, stream>>>(p_att, na_ws);
  k_huc<<<192, 256, 0, stream>>>(xp, na_ws, hu_ws);
  k_qdot<<<12, 256, 0, stream>>>(na_ws, hu_ws, dc_q_w, dc_q_b, dc_p_w, qdot);
  k_keymma<<<18, 256, 0, stream>>>(xbf, dc_k_w, dc_k_b, dc_p_w, keydot);
  k_depatt<<<108, 256, 0, stream>>>(p_att, keydot, qdot, dc_p_b, dep_att);
  k_rpx<<<72, 256, 0, stream>>>(xbf, dp_proj, rpx);
  k_convfused<<<576, 256, 0, stream>>>(xbf, wt, w0, dep_att, h_att,
                                       ctx_w2, du_a2, dl_a2, ctx_b2, du_a2b, dl_a2b,
                                       out_fdep, out_du, out_dl, att_sm, da_u, da_l);
  k_yhv<<<108, 256, 0, stream>>>(p_nodes, dp_r1, yhv_ws);
  k_msgs_edge<<<540, 256, 0, stream>>>(att_sm, dep_att, rpx, yhv_ws,
                                       dp_r1, dp_r2, dp_r2b, msg_ws);
  k_parts_gru<<<108, 256, 0, stream>>>(h_nodes, p_nodes, h_att, da_u, da_l,
                                       du_r1, du_r2, dl_r1, dl_r2, msg_ws, alpha,
                                       gru_gw, gru_gb, gru_cw, out_pnew);
  k_gru0<<<18, 256, 0, stream>>>(h_nodes, p_nodes, gru_gw, gru_gb, gru_cw, out_pnew);
}